// Round 20
// baseline (332.047 us; speedup 1.0000x reference)
//
#include <hip/hip_runtime.h>
#include <hip/hip_bf16.h>
#include <stdint.h>
#include <stddef.h>

#define SEQL 2048
#define DIMSZ 2048
#define HN 16
#define DKD 128
#define DVD 128
#define QSCALE 0.08838834764831843f   // 128^-0.5

typedef __attribute__((ext_vector_type(4))) float f32x4;
typedef __attribute__((ext_vector_type(2))) float f32x2;
typedef __attribute__((ext_vector_type(8))) short bf16x8;

__device__ __forceinline__ float sigmoid_f(float x) { return 1.f / (1.f + __expf(-x)); }
__device__ __forceinline__ float bf2f(short s) {
  union { float f; unsigned int u; } t; t.u = ((unsigned int)(unsigned short)s) << 16; return t.f;
}

// ---------------- bf16 GEMM: C[M,N] (f32) = A[M,K]bf16 @ Bt[N,K]bf16 ----------------
#define BM 128
#define BN 128
#define BKK 64

__global__ __launch_bounds__(256) void gemm_bt(
    const __hip_bfloat16* __restrict__ A, const __hip_bfloat16* __restrict__ B,
    float* __restrict__ C, int M, int N, int lda, int ldb, int klen, int accum)
{
  __shared__ __hip_bfloat16 As[BM * BKK];
  __shared__ __hip_bfloat16 Bs[BN * BKK];
  const int tid = threadIdx.x;
  const int lane = tid & 63;
  const int w = tid >> 6;
  const int wm = w >> 1, wn = w & 1;            // 2x2 wave grid, 64x64 each
  const int m0 = blockIdx.y * BM, n0 = blockIdx.x * BN;
  const int l15 = lane & 15, l4 = lane >> 4;
  const int kbase = blockIdx.z * klen;

  f32x4 acc[4][4] = {};

  for (int k0 = kbase; k0 < kbase + klen; k0 += BKK) {
#pragma unroll
    for (int i = 0; i < 4; ++i) {
      const int c = (w * 4 + i) * 64 + lane;     // chunk id, 16B each; 8 chunks/row
      const int row = c >> 3;
      const int colb = (c & 7) * 8;
      __builtin_amdgcn_global_load_lds(
          (const __attribute__((address_space(1))) void*)(A + (size_t)(m0 + row) * lda + k0 + colb),
          (__attribute__((address_space(3))) void*)(As + (size_t)c * 8), 16, 0, 0);
      __builtin_amdgcn_global_load_lds(
          (const __attribute__((address_space(1))) void*)(B + (size_t)(n0 + row) * ldb + k0 + colb),
          (__attribute__((address_space(3))) void*)(Bs + (size_t)c * 8), 16, 0, 0);
    }
    __syncthreads();
#pragma unroll
    for (int kk = 0; kk < BKK; kk += 32) {
      bf16x8 af[4], bfv[4];
#pragma unroll
      for (int mi = 0; mi < 4; ++mi)
        af[mi] = *(const bf16x8*)(As + (wm * 64 + mi * 16 + l15) * BKK + kk + l4 * 8);
#pragma unroll
      for (int ni = 0; ni < 4; ++ni)
        bfv[ni] = *(const bf16x8*)(Bs + (wn * 64 + ni * 16 + l15) * BKK + kk + l4 * 8);
#pragma unroll
      for (int mi = 0; mi < 4; ++mi)
#pragma unroll
        for (int ni = 0; ni < 4; ++ni)
          acc[mi][ni] = __builtin_amdgcn_mfma_f32_16x16x32_bf16(af[mi], bfv[ni], acc[mi][ni], 0, 0, 0);
    }
    __syncthreads();
  }

  float* Cz = C + (size_t)blockIdx.z * M * N;
#pragma unroll
  for (int mi = 0; mi < 4; ++mi) {
#pragma unroll
    for (int ni = 0; ni < 4; ++ni) {
      const int row = m0 + wm * 64 + mi * 16 + l4 * 4;
      const int col = n0 + wn * 64 + ni * 16 + l15;
#pragma unroll
      for (int r = 0; r < 4; ++r) {
        size_t idx = (size_t)(row + r) * N + col;
        if (accum) Cz[idx] += acc[mi][ni][r];
        else Cz[idx] = acc[mi][ni][r];
      }
    }
  }
}

// ---------------- 256x192 6-phase GEMM (T2+T3+T4+T5), bf16 out; grid fills 256 CUs ----------------
__global__ __launch_bounds__(512, 1) void gemm_bt192(
    const __hip_bfloat16* __restrict__ A, const __hip_bfloat16* __restrict__ B,
    __hip_bfloat16* __restrict__ Cb, int N, int lda, int ldb, int NT)
{
  __shared__ __hip_bfloat16 lds[57344];   // 112 KiB
  const int tid = threadIdx.x;
  const int w = tid >> 6, lane = tid & 63;
  const int wm = w >> 2, wn = w & 3;
  const int l15 = lane & 15, l4 = lane >> 4;
  const int m0 = blockIdx.y * 256, n0 = blockIdx.x * 192;

  f32x4 acc[8][3] = {};
  bf16x8 a[4][2], b[2];

  auto stage_a = [&](int half, int t1) {
    const int buf = t1 & 1;
    const int k0n = ((t1 < NT) ? t1 : 0) * 64;
#pragma unroll
    for (int i = 0; i < 2; ++i) {
      const int c = i * 512 + tid;           // 1024 chunks per half
      const int l = half * 128 + (c >> 3);
      const int kcs = (c & 7) ^ (l & 7);
      const int grow = ((l >> 6) & 1) * 128 + (l >> 7) * 64 + (l & 63);
      __builtin_amdgcn_global_load_lds(
          (const __attribute__((address_space(1))) void*)(A + (size_t)(m0 + grow) * lda + k0n + kcs * 8),
          (__attribute__((address_space(3))) void*)(lds + (size_t)buf * 28672 + half * 8192 + (size_t)c * 8),
          16, 0, 0);
    }
  };
  auto stage_b = [&](int j, int t1) {
    const int buf = t1 & 1;
    const int k0n = ((t1 < NT) ? t1 : 0) * 64;
    const int c = tid;                       // 512 chunks per third
    const int l = j * 64 + (c >> 3);
    const int kcs = (c & 7) ^ (l & 7);
    __builtin_amdgcn_global_load_lds(
        (const __attribute__((address_space(1))) void*)(B + (size_t)(n0 + l) * ldb + k0n + kcs * 8),
        (__attribute__((address_space(3))) void*)(lds + (size_t)buf * 28672 + 16384 + j * 4096 + (size_t)c * 8),
        16, 0, 0);
  };

  auto phase = [&](size_t cb, int MQ, int NQ, bool needA) {
    if (needA) {
#pragma unroll
      for (int m2 = 0; m2 < 4; ++m2)
#pragma unroll
        for (int ks = 0; ks < 2; ++ks) {
          const int la = MQ * 128 + wm * 64 + m2 * 16 + l15;
          const int kc = ks * 4 + l4;
          a[m2][ks] = *(const bf16x8*)(lds + cb + la * 64 + (kc ^ (la & 7)) * 8);
        }
    }
#pragma unroll
    for (int ks = 0; ks < 2; ++ks) {
      const int lb = NQ * 64 + wn * 16 + l15;
      const int kc = ks * 4 + l4;
      b[ks] = *(const bf16x8*)(lds + cb + 16384 + lb * 64 + (kc ^ (lb & 7)) * 8);
    }
    __builtin_amdgcn_s_setprio(1);
#pragma unroll
    for (int m2 = 0; m2 < 4; ++m2)
#pragma unroll
      for (int ks = 0; ks < 2; ++ks)
        acc[MQ * 4 + m2][NQ] = __builtin_amdgcn_mfma_f32_16x16x32_bf16(
            a[m2][ks], b[ks], acc[MQ * 4 + m2][NQ], 0, 0, 0);
    __builtin_amdgcn_s_setprio(0);
  };

  stage_a(0, 0); stage_a(1, 0); stage_b(0, 0); stage_b(1, 0); stage_b(2, 0);

  for (int t = 0; t < NT; ++t) {
    const size_t cb = (size_t)(t & 1) * 28672;
    stage_a(0, t + 1);
    asm volatile("s_waitcnt vmcnt(4)" ::: "memory");
    __builtin_amdgcn_s_barrier();
    __builtin_amdgcn_sched_barrier(0);
    phase(cb, 0, 0, true);
    __builtin_amdgcn_s_barrier();
    stage_a(1, t + 1);
    asm volatile("s_waitcnt vmcnt(5)" ::: "memory");
    __builtin_amdgcn_s_barrier();
    __builtin_amdgcn_sched_barrier(0);
    phase(cb, 0, 1, false);
    __builtin_amdgcn_s_barrier();
    stage_b(0, t + 1);
    asm volatile("s_waitcnt vmcnt(5)" ::: "memory");
    __builtin_amdgcn_s_barrier();
    __builtin_amdgcn_sched_barrier(0);
    phase(cb, 0, 2, false);
    __builtin_amdgcn_s_barrier();
    stage_b(1, t + 1);
    __builtin_amdgcn_s_barrier();
    __builtin_amdgcn_sched_barrier(0);
    phase(cb, 1, 0, true);
    __builtin_amdgcn_s_barrier();
    stage_b(2, t + 1);
    __builtin_amdgcn_s_barrier();
    __builtin_amdgcn_sched_barrier(0);
    phase(cb, 1, 1, false);
    __builtin_amdgcn_s_barrier();
    __builtin_amdgcn_s_barrier();
    __builtin_amdgcn_sched_barrier(0);
    phase(cb, 1, 2, false);
    __builtin_amdgcn_s_barrier();
  }
  asm volatile("s_waitcnt vmcnt(0)" ::: "memory");

#pragma unroll
  for (int mi = 0; mi < 8; ++mi)
#pragma unroll
    for (int nq = 0; nq < 3; ++nq) {
      const int row = m0 + wm * 128 + mi * 16 + l4 * 4;
      const int col = n0 + nq * 64 + wn * 16 + l15;
#pragma unroll
      for (int r = 0; r < 4; ++r)
        Cb[(size_t)(row + r) * N + col] = __float2bfloat16(acc[mi][nq][r]);
    }
}

// ---------------- fused split-precision GEMM: C = Ah@Bh + Ah@Bl + Al@Bh ----------------
// Blocks with n0 >= nbl skip the Bl stream entirely (Bl rows known zero there).
__global__ __launch_bounds__(256) void gemm_btsplit(
    const __hip_bfloat16* __restrict__ Ah, const __hip_bfloat16* __restrict__ Al,
    const __hip_bfloat16* __restrict__ Bh, const __hip_bfloat16* __restrict__ Bl,
    float* __restrict__ C, int M, int N, int lda, int ldb, int klen, int nbl)
{
  __shared__ __hip_bfloat16 Ash[BM * BKK];
  __shared__ __hip_bfloat16 Asl[BM * BKK];
  __shared__ __hip_bfloat16 Bsh[BN * BKK];
  __shared__ __hip_bfloat16 Bsl[BN * BKK];
  const int tid = threadIdx.x;
  const int lane = tid & 63;
  const int w = tid >> 6;
  const int wm = w >> 1, wn = w & 1;
  const int m0 = blockIdx.y * BM, n0 = blockIdx.x * BN;
  const int l15 = lane & 15, l4 = lane >> 4;
  const int kbase = blockIdx.z * klen;
  const bool do_bl = (n0 < nbl);

  f32x4 acc[4][4] = {};

  for (int k0 = kbase; k0 < kbase + klen; k0 += BKK) {
#pragma unroll
    for (int i = 0; i < 4; ++i) {
      const int c = (w * 4 + i) * 64 + lane;
      const int row = c >> 3;
      const int colb = (c & 7) * 8;
      const size_t go = (size_t)(m0 + row) * lda + k0 + colb;
      const size_t gn = (size_t)(n0 + row) * ldb + k0 + colb;
      __builtin_amdgcn_global_load_lds(
          (const __attribute__((address_space(1))) void*)(Ah + go),
          (__attribute__((address_space(3))) void*)(Ash + (size_t)c * 8), 16, 0, 0);
      __builtin_amdgcn_global_load_lds(
          (const __attribute__((address_space(1))) void*)(Al + go),
          (__attribute__((address_space(3))) void*)(Asl + (size_t)c * 8), 16, 0, 0);
      __builtin_amdgcn_global_load_lds(
          (const __attribute__((address_space(1))) void*)(Bh + gn),
          (__attribute__((address_space(3))) void*)(Bsh + (size_t)c * 8), 16, 0, 0);
      if (do_bl)
        __builtin_amdgcn_global_load_lds(
            (const __attribute__((address_space(1))) void*)(Bl + gn),
            (__attribute__((address_space(3))) void*)(Bsl + (size_t)c * 8), 16, 0, 0);
    }
    __syncthreads();
#pragma unroll
    for (int kk = 0; kk < BKK; kk += 32) {
      bf16x8 afh[4], afl[4], bfh[4], bfl[4];
#pragma unroll
      for (int mi = 0; mi < 4; ++mi) {
        const int ao = (wm * 64 + mi * 16 + l15) * BKK + kk + l4 * 8;
        afh[mi] = *(const bf16x8*)(Ash + ao);
        afl[mi] = *(const bf16x8*)(Asl + ao);
      }
#pragma unroll
      for (int ni = 0; ni < 4; ++ni) {
        const int bo = (wn * 64 + ni * 16 + l15) * BKK + kk + l4 * 8;
        bfh[ni] = *(const bf16x8*)(Bsh + bo);
        bfl[ni] = *(const bf16x8*)(Bsl + bo);
      }
#pragma unroll
      for (int mi = 0; mi < 4; ++mi)
#pragma unroll
        for (int ni = 0; ni < 4; ++ni) {
          acc[mi][ni] = __builtin_amdgcn_mfma_f32_16x16x32_bf16(afh[mi], bfh[ni], acc[mi][ni], 0, 0, 0);
          if (do_bl)
            acc[mi][ni] = __builtin_amdgcn_mfma_f32_16x16x32_bf16(afh[mi], bfl[ni], acc[mi][ni], 0, 0, 0);
          acc[mi][ni] = __builtin_amdgcn_mfma_f32_16x16x32_bf16(afl[mi], bfh[ni], acc[mi][ni], 0, 0, 0);
        }
    }
    __syncthreads();
  }

  float* Cz = C + (size_t)blockIdx.z * M * N;
#pragma unroll
  for (int mi = 0; mi < 4; ++mi) {
#pragma unroll
    for (int ni = 0; ni < 4; ++ni) {
      const int row = m0 + wm * 64 + mi * 16 + l4 * 4;
      const int col = n0 + wn * 64 + ni * 16 + l15;
#pragma unroll
      for (int r = 0; r < 4; ++r)
        Cz[(size_t)(row + r) * N + col] = acc[mi][ni][r];
    }
  }
}

// ---------------- merged weight transposes + x split-cast (one launch) ----------------
__global__ __launch_bounds__(256) void prep_all_kernel(
    const float* __restrict__ x, __hip_bfloat16* __restrict__ xb, __hip_bfloat16* __restrict__ xlo,
    const float* __restrict__ Wq, const float* __restrict__ Wk,
    const float* __restrict__ Wv, const float* __restrict__ Wo,
    __hip_bfloat16* __restrict__ WqkvT, __hip_bfloat16* __restrict__ WoT,
    const float* __restrict__ Wf1, const float* __restrict__ Wg1,
    __hip_bfloat16* __restrict__ fg1h, __hip_bfloat16* __restrict__ fg1l,
    const float* __restrict__ Wf2, const float* __restrict__ Wg2,
    __hip_bfloat16* __restrict__ f2h, __hip_bfloat16* __restrict__ f2l,
    __hip_bfloat16* __restrict__ g2h)
{
  __shared__ float tile[32][33];
  const int bid = blockIdx.x;
  const int tid = threadIdx.x;
  const int tc = tid & 31, tr = tid >> 5;

  if (bid < 16384) {
    const int z = bid >> 12, rem = bid & 4095;
    const int c0 = (rem & 63) * 32, r0 = (rem >> 6) * 32;
    const float* in = (z == 0) ? Wq : (z == 1) ? Wk : (z == 2) ? Wv : Wo;
    __hip_bfloat16* outT = (z < 3) ? (WqkvT + (size_t)z * 2048 * 2048) : WoT;
#pragma unroll
    for (int i = 0; i < 4; ++i)
      tile[tr + i * 8][tc] = in[(size_t)(r0 + tr + i * 8) * 2048 + c0 + tc];
    __syncthreads();
#pragma unroll
    for (int i = 0; i < 4; ++i)
      outT[(size_t)(c0 + tr + i * 8) * 2048 + r0 + tc] = __float2bfloat16(tile[tc][tr + i * 8]);
  } else if (bid < 16896) {
    const int rem = bid - 16384;
    const int z = rem >> 8, within = rem & 255;
    const int c0 = (within & 3) * 32, r0 = (within >> 2) * 32;   // c over 128, r over 2048
    const float* in = z ? Wg1 : Wf1;
    const size_t base = (size_t)z * 128 * 2048;
#pragma unroll
    for (int i = 0; i < 4; ++i)
      tile[tr + i * 8][tc] = in[(size_t)(r0 + tr + i * 8) * 128 + c0 + tc];
    __syncthreads();
#pragma unroll
    for (int i = 0; i < 4; ++i) {
      float val = tile[tc][tr + i * 8];
      __hip_bfloat16 h = __float2bfloat16(val);
      size_t oi = base + (size_t)(c0 + tr + i * 8) * 2048 + r0 + tc;
      fg1h[oi] = h;
      if (!z) fg1l[oi] = __float2bfloat16(val - __bfloat162float(h));
    }
  } else if (bid < 17408) {
    const int rem = bid - 16896;
    const int z = rem >> 8, within = rem & 255;
    const int c0 = (within & 63) * 32, r0 = (within >> 6) * 32;  // c over 2048, r over 128
    const float* in = z ? Wg2 : Wf2;
#pragma unroll
    for (int i = 0; i < 4; ++i)
      tile[tr + i * 8][tc] = in[(size_t)(r0 + tr + i * 8) * 2048 + c0 + tc];
    __syncthreads();
#pragma unroll
    for (int i = 0; i < 4; ++i) {
      float val = tile[tc][tr + i * 8];
      __hip_bfloat16 h = __float2bfloat16(val);
      size_t oi = (size_t)(c0 + tr + i * 8) * 128 + r0 + tc;
      if (z == 0) { f2h[oi] = h; f2l[oi] = __float2bfloat16(val - __bfloat162float(h)); }
      else g2h[oi] = h;
    }
  } else {
    const int idx = (bid - 17408) * 256 + tid;   // exactly covers S2/4
    f32x4 v = *(const f32x4*)(x + (size_t)idx * 4);
    union { __hip_bfloat16 b[4]; unsigned long long u; } ph, pl;
#pragma unroll
    for (int j = 0; j < 4; ++j) {
      float f = v[j];
      __hip_bfloat16 hh = __float2bfloat16(f);
      ph.b[j] = hh;
      pl.b[j] = __float2bfloat16(f - __bfloat162float(hh));
    }
    *(unsigned long long*)((char*)xb + (size_t)idx * 8) = ph.u;
    *(unsigned long long*)((char*)xlo + (size_t)idx * 8) = pl.u;
  }
}

// ---------------- split-K reduce (8 partials) -> bf16 hi+lo, fused with beta ----------------
__global__ __launch_bounds__(256) void reduce8_beta_kernel(
    const float* __restrict__ part, __hip_bfloat16* __restrict__ hi,
    __hip_bfloat16* __restrict__ lo, size_t chunk,
    const float* __restrict__ x, const float* __restrict__ Wb, float* __restrict__ betaT)
{
  const int tid = threadIdx.x;
  if (blockIdx.x < 512) {
    int idx = blockIdx.x * 256 + tid;
    f32x4 a = *(const f32x4*)(part + (size_t)idx * 4);
#pragma unroll
    for (int z = 1; z < 8; ++z) {
      f32x4 b = *(const f32x4*)(part + z * chunk + (size_t)idx * 4);
      a.x += b.x; a.y += b.y; a.z += b.z; a.w += b.w;
    }
    union { __hip_bfloat16 b[4]; unsigned long long u; } ph, pl;
#pragma unroll
    for (int j = 0; j < 4; ++j) {
      float f = a[j];
      __hip_bfloat16 hh = __float2bfloat16(f);
      ph.b[j] = hh;
      pl.b[j] = __float2bfloat16(f - __bfloat162float(hh));
    }
    *(unsigned long long*)((char*)hi + (size_t)idx * 8) = ph.u;
    *(unsigned long long*)((char*)lo + (size_t)idx * 8) = pl.u;
  } else {
    int idx = (blockIdx.x - 512) * 256 + tid;    // 0..32767
    int s = idx >> 4, h = idx & 15;
    const float* xr = x + (size_t)s * DIMSZ;
    float acc = 0.f;
    for (int d = 0; d < DIMSZ; d += 4) {
      f32x4 xv = *(const f32x4*)(xr + d);
      acc = fmaf(xv.x, Wb[(size_t)(d + 0) * HN + h], acc);
      acc = fmaf(xv.y, Wb[(size_t)(d + 1) * HN + h], acc);
      acc = fmaf(xv.z, Wb[(size_t)(d + 2) * HN + h], acc);
      acc = fmaf(xv.w, Wb[(size_t)(d + 3) * HN + h], acc);
    }
    betaT[(size_t)h * SEQL + s] = 1.f / (1.f + expf(-acc));
  }
}

// ---------------- fused prep + chunk-local precompute (C=32); qkv in bf16 ----------------
#define SL20(r, d) ((r) * 160 + ((d) >> 4) * 20 + ((d) & 15))

__global__ __launch_bounds__(256) void kda_pref(
    const __hip_bfloat16* __restrict__ qkv, const float* __restrict__ ve,
    const float* __restrict__ lam,
    const float* __restrict__ cwq, const float* __restrict__ cwk, const float* __restrict__ cwv,
    const float* __restrict__ gbuf,
    const float* __restrict__ dtb, const float* __restrict__ A_log,
    const float* __restrict__ betaT,
    __hip_bfloat16* __restrict__ Xgh, __hip_bfloat16* __restrict__ KTh,
    __hip_bfloat16* __restrict__ uvS, __hip_bfloat16* __restrict__ olocS,
    float* __restrict__ Pg)
{
  __shared__ float GL2[32 * 160];
  __shared__ float kL2[32 * 160];
  __shared__ float qL2[32 * 132];
  __shared__ float vL2[32 * 128];
  __shared__ float ALB[32][33];      // lower: A; upper [i][t]: B[t][i] (i<t)
  __shared__ float Bdiag[32], betaL[32];
  __shared__ float csumW[4 * 128];

  const int bid = blockIdx.x;
  const int h = bid >> 6, cc = bid & 63;
  const int tid = threadIdx.x;
  const int w = tid >> 6, lane = tid & 63;
  const size_t hc = (size_t)h * 64 + cc;
  const float Aexp = __expf(A_log[h]);

  // ======== phase 1: conv + silu + mix + l2norm + glog ========
  {
    const int c = lane * 2;                 // col pair
    const int r0g = cc * 32 + w * 8;        // global row base for this wave
    const int cg = h * 128 + c;

    f32x4 wq0 = *(const f32x4*)(cwq + (size_t)cg * 4), wq1 = *(const f32x4*)(cwq + (size_t)(cg + 1) * 4);
    f32x4 wk0 = *(const f32x4*)(cwk + (size_t)cg * 4), wk1 = *(const f32x4*)(cwk + (size_t)(cg + 1) * 4);
    f32x4 wv0 = *(const f32x4*)(cwv + (size_t)cg * 4), wv1 = *(const f32x4*)(cwv + (size_t)(cg + 1) * 4);
    f32x2 dt2 = *(const f32x2*)(dtb + cg);
    const float l0 = lam[0], l1 = lam[1];

    f32x2 xqr[11], xkr[11], xvr[11];
#pragma unroll
    for (int i = 0; i < 11; ++i) {
      const int sr = r0g - 3 + i;
      if (sr >= 0) {
        const size_t ro = (size_t)sr * 6144 + cg;
        unsigned int uq = *(const unsigned int*)(qkv + ro);
        unsigned int uk = *(const unsigned int*)(qkv + 2048 + ro);
        unsigned int uv2 = *(const unsigned int*)(qkv + 4096 + ro);
        xqr[i].x = bf2f((short)uq);   xqr[i].y = bf2f((short)(uq >> 16));
        xkr[i].x = bf2f((short)uk);   xkr[i].y = bf2f((short)(uk >> 16));
        xvr[i].x = bf2f((short)uv2);  xvr[i].y = bf2f((short)(uv2 >> 16));
      } else {
        xqr[i].x = xqr[i].y = xkr[i].x = xkr[i].y = xvr[i].x = xvr[i].y = 0.f;
      }
    }

    float gl0[8], gl1[8];
#pragma unroll
    for (int i = 0; i < 8; ++i) {
      const int rr = r0g + i;
      const int lr = w * 8 + i;
      float aq0 = 0, aq1 = 0, ak0 = 0, ak1 = 0, av0 = 0, av1 = 0;
#pragma unroll
      for (int j = 0; j < 4; ++j) {
        aq0 = fmaf(xqr[i + j].x, wq0[j], aq0); aq1 = fmaf(xqr[i + j].y, wq1[j], aq1);
        ak0 = fmaf(xkr[i + j].x, wk0[j], ak0); ak1 = fmaf(xkr[i + j].y, wk1[j], ak1);
        av0 = fmaf(xvr[i + j].x, wv0[j], av0); av1 = fmaf(xvr[i + j].y, wv1[j], av1);
      }
      float yq0 = aq0 * sigmoid_f(aq0), yq1 = aq1 * sigmoid_f(aq1);
      float yk0 = ak0 * sigmoid_f(ak0), yk1 = ak1 * sigmoid_f(ak1);
      float yv0 = av0 * sigmoid_f(av0), yv1 = av1 * sigmoid_f(av1);

      f32x2 vev = *(const f32x2*)(ve + ((size_t)rr * HN + h) * 128 + c);
      float v0 = l0 * yv0 + l1 * vev.x;
      float v1 = l0 * yv1 + l1 * vev.y;

      float ssq = yq0 * yq0 + yq1 * yq1;
      float ssk = yk0 * yk0 + yk1 * yk1;
#pragma unroll
      for (int off = 32; off > 0; off >>= 1) {
        ssq += __shfl_xor(ssq, off);
        ssk += __shfl_xor(ssk, off);
      }
      float rq = rsqrtf(ssq + 1e-6f) * QSCALE;
      float rk = rsqrtf(ssk + 1e-6f);

      f32x2 kk; kk.x = yk0 * rk; kk.y = yk1 * rk;
      f32x2 qq; qq.x = yq0 * rq; qq.y = yq1 * rq;
      f32x2 vv; vv.x = v0; vv.y = v1;
      *(f32x2*)&kL2[SL20(lr, c)] = kk;
      *(f32x2*)&qL2[lr * 132 + c] = qq;
      *(f32x2*)&vL2[lr * 128 + c] = vv;

      f32x2 gv = *(const f32x2*)(gbuf + (size_t)rr * 2048 + cg);
      float g0 = gv.x + dt2.x, g1 = gv.y + dt2.y;
      float sp0 = (g0 > 20.f) ? g0 : __logf(1.f + __expf(g0));
      float sp1 = (g1 > 20.f) ? g1 : __logf(1.f + __expf(g1));
      gl0[i] = -Aexp * sp0;
      gl1[i] = -Aexp * sp1;
    }
    // per-wave cumsum
    {
      float r0 = 0.f, r1 = 0.f;
#pragma unroll
      for (int i = 0; i < 8; ++i) { r0 += gl0[i]; gl0[i] = r0; r1 += gl1[i]; gl1[i] = r1; }
      csumW[w * 128 + c] = r0;
      csumW[w * 128 + c + 1] = r1;
    }
    if (tid < 32) betaL[tid] = betaT[(size_t)h * SEQL + cc * 32 + tid];
    __syncthreads();
    // cross-wave prefix, write GL
    {
      float p0 = 0.f, p1 = 0.f;
      for (int wp = 0; wp < w; ++wp) { p0 += csumW[wp * 128 + c]; p1 += csumW[wp * 128 + c + 1]; }
#pragma unroll
      for (int i = 0; i < 8; ++i) {
        f32x2 gg; gg.x = gl0[i] + p0; gg.y = gl1[i] + p1;
        *(f32x2*)&GL2[SL20(w * 8 + i, c)] = gg;
      }
    }
  }
  __syncthreads();

  // ======== phase 2: rebased MFMA inter-blocks + scalar 8x8 triangles ========
  {
    const int m = lane & 15, quad = lane >> 4;
    // ---- MFMA job: w0=A16, w1=B16, w2=A8pack, w3=B8pack ----
    {
      const bool useQ = (w & 1);
      int tL, iR, ref;
      if (w < 2)      { tL = 16 + m; iR = m;     ref = 15; }
      else if (m < 8) { tL = 8 + m;  iR = m;     ref = 7;  }
      else            { tL = 16 + m; iR = 8 + m; ref = 23; }

      f32x4 accM = {};
#pragma unroll
      for (int kk = 0; kk < 4; ++kk) {
        const int d0 = kk * 32 + quad * 8;
        const int slb = (d0 >> 4) * 20 + (d0 & 15);
        f32x4 gL0 = *(const f32x4*)&GL2[tL * 160 + slb];
        f32x4 gL1 = *(const f32x4*)&GL2[tL * 160 + slb + 4];
        f32x4 gR0 = *(const f32x4*)&GL2[iR * 160 + slb];
        f32x4 gR1 = *(const f32x4*)&GL2[iR * 160 + slb + 4];
        f32x4 gF0 = *(const f32x4*)&GL2[ref * 160 + slb];
        f32x4 gF1 = *(const f32x4*)&GL2[ref * 160 + slb + 4];
        f32x4 kR0 = *(const f32x4*)&kL2[iR * 160 + slb];
        f32x4 kR1 = *(const f32x4*)&kL2[iR * 160 + slb + 4];
        f32x4 vL0, vL1;
        if (useQ) {
          vL0 = *(const f32x4*)&qL2[tL * 132 + d0];
          vL1 = *(const f32x4*)&qL2[tL * 132 + d0 + 4];
        } else {
          vL0 = *(const f32x4*)&kL2[tL * 160 + slb];
          vL1 = *(const f32x4*)&kL2[tL * 160 + slb + 4];
        }
        union { bf16x8 v; unsigned short u[8]; } lh, ll, rh, rl;
#pragma unroll
        for (int j = 0; j < 4; ++j) {
          float fl = vL0[j] * __expf(gL0[j] - gF0[j]);
          float fr = kR0[j] * __expf(gF0[j] - gR0[j]);
          __hip_bfloat16 h1 = __float2bfloat16(fl);
          __hip_bfloat16 h1l = __float2bfloat16(fl - __bfloat162float(h1));
          __hip_bfloat16 h2 = __float2bfloat16(fr);
          __hip_bfloat16 h2l = __float2bfloat16(fr - __bfloat162float(h2));
          lh.u[j] = *(const unsigned short*)&h1; ll.u[j] = *(const unsigned short*)&h1l;
          rh.u[j] = *(const unsigned short*)&h2; rl.u[j] = *(const unsigned short*)&h2l;
          float fl2 = vL1[j] * __expf(gL1[j] - gF1[j]);
          float fr2 = kR1[j] * __expf(gF1[j] - gR1[j]);
          __hip_bfloat16 h3 = __float2bfloat16(fl2);
          __hip_bfloat16 h3l = __float2bfloat16(fl2 - __bfloat162float(h3));
          __hip_bfloat16 h4 = __float2bfloat16(fr2);
          __hip_bfloat16 h4l = __float2bfloat16(fr2 - __bfloat162float(h4));
          lh.u[4 + j] = *(const unsigned short*)&h3; ll.u[4 + j] = *(const unsigned short*)&h3l;
          rh.u[4 + j] = *(const unsigned short*)&h4; rl.u[4 + j] = *(const unsigned short*)&h4l;
        }
        accM = __builtin_amdgcn_mfma_f32_16x16x32_bf16(lh.v, rh.v, accM, 0, 0, 0);
        accM = __builtin_amdgcn_mfma_f32_16x16x32_bf16(lh.v, rl.v, accM, 0, 0, 0);
        accM = __builtin_amdgcn_mfma_f32_16x16x32_bf16(ll.v, rh.v, accM, 0, 0, 0);
      }
#pragma unroll
      for (int r = 0; r < 4; ++r) {
        const int row = quad * 4 + r;
        const int col = m;
        if (w < 2) {
          if (useQ) ALB[col][16 + row] = accM[r];
          else      ALB[16 + row][col] = accM[r];
        } else if ((row < 8) == (col < 8)) {
          const int t = (row < 8) ? (8 + row) : (16 + row);
          const int i = (col < 8) ? col : (8 + col);
          if (useQ) ALB[i][t] = accM[r];
          else      ALB[t][i] = accM[r];
        }
      }
    }
    // ---- scalar 8x8 triangle T_w (rows [8w, 8w+8)) ----
    {
      const int tg = lane >> 3, s8 = lane & 7;
      const int base = w * 8;
      const int tt = base + tg;
      const int ds = s8 * 20;

      float Gt[16], kt[16], qt[16];
#pragma unroll
      for (int j = 0; j < 16; j += 4) {
        *(f32x4*)&Gt[j] = *(const f32x4*)&GL2[tt * 160 + ds + j];
        *(f32x4*)&kt[j] = *(const f32x4*)&kL2[tt * 160 + ds + j];
        *(f32x4*)&qt[j] = *(const f32x4*)&qL2[tt * 132 + s8 * 16 + j];
      }
      {
        float sA = 0.f, sB = 0.f;
#pragma unroll
        for (int j = 0; j < 16; ++j) { sA = fmaf(kt[j], kt[j], sA); sB = fmaf(qt[j], kt[j], sB); }
        sA += __shfl_xor(sA, 1); sA += __shfl_xor(sA, 2); sA += __shfl_xor(sA, 4);
        sB += __shfl_xor(sB, 1); sB += __shfl_xor(sB, 2); sB += __shfl_xor(sB, 4);
        if (s8 == 0) { ALB[tt][tt] = sA; Bdiag[tt] = sB; }
      }
      for (int i = base; i < base + 7; ++i) {
        if (i < tt) {
          float sA = 0.f, sB = 0.f;
#pragma unroll
          for (int jj = 0; jj < 4; ++jj) {
            f32x4 Gi = *(const f32x4*)&GL2[i * 160 + ds + jj * 4];
            f32x4 ki = *(const f32x4*)&kL2[i * 160 + ds + jj * 4];
#pragma unroll
            for (int u = 0; u < 4; ++u) {
              float e = __expf(Gt[jj * 4 + u] - Gi[u]);
              float kid = ki[u] * e;
              sA = fmaf(kt[jj * 4 + u], kid, sA);
              sB = fmaf(qt[jj * 4 + u], kid, sB);
            }
          }
          sA += __shfl_xor(sA, 1); sA += __shfl_xor(sA, 2); sA += __shfl_xor(sA, 4);
          sB += __shfl_xor(sB, 1); sB += __shfl_xor(sB, 2); sB += __shfl_xor(sB, 4);
          if (s8 == 0) { ALB[tt][i] = sA; ALB[i][tt] = sB; }
        }
      }
    }
  }
  __syncthreads();

  // ======== phase 3: KbarT + role-split substitution; uv/oloc stored bf16 ========
  const int col = tid & 127, half = tid >> 7;
  const size_t rowbase = (size_t)(cc * 32) * 2048 + h * 128 + col;
  const int rbase = half * 16;
  {
    const float g31 = GL2[SL20(31, col)];
    size_t kb = hc * 4096 + (size_t)col * 32;
#pragma unroll
    for (int i = 0; i < 16; ++i) {
      int r = rbase + i;
      float kv = kL2[SL20(r, col)] * __expf(g31 - GL2[SL20(r, col)]);
      KTh[kb + r] = __float2bfloat16(kv);
    }
  }

  float expg[32];
#pragma unroll
  for (int r = 0; r < 32; ++r) expg[r] = __expf(GL2[SL20(r, col)]);

  if (half == 0) {
    // uv recurrence + oloc
    float uvr[32];
#pragma unroll
    for (int r = 0; r < 32; ++r) {
      float suv = 0.f;
#pragma unroll
      for (int j = 0; j < 32; ++j) {
        if (j < r) suv = fmaf(ALB[r][j], uvr[j], suv);
      }
      uvr[r] = betaL[r] * (vL2[r * 128 + col] - suv);
      uvS[rowbase + (size_t)r * 2048] = __float2bfloat16(uvr[r]);
    }
#pragma unroll
    for (int r = 0; r < 32; ++r) {
      float ol = Bdiag[r] * uvr[r];
#pragma unroll
      for (int j = 0; j < 32; ++j) {
        if (j < r) ol = fmaf(ALB[j][r], uvr[j], ol);
      }
      olocS[rowbase + (size_t)r * 2048] = __float2bfloat16(ol);
    }
    Pg[hc * 128 + col] = expg[31];
  } else {
    // w recurrence + Qt
    float wr[32];
#pragma unroll
    for (int r = 0; r < 32; ++r) {
      float sw = 0.f;
#pragma unroll
      for (int j = 0; j < 32; ++j) {
        if (j < r) sw = fmaf(ALB[r][j], wr[j], sw);
      }
      wr[r] = betaL[r] * (kL2[SL20(r, col)] * expg[r] - sw);
      Xgh[hc * 8192 + (size_t)(32 + r) * 128 + col] = __float2bfloat16(wr[r]);
    }
#pragma unroll
    for (int r = 0; r < 32; ++r) {
      float qtv = qL2[r * 132 + col] * expg[r];
      qtv = fmaf(-Bdiag[r], wr[r], qtv);
#pragma unroll
      for (int j = 0; j < 32; ++j) {
        if (j < r) qtv = fmaf(-ALB[j][r], wr[j], qtv);
      }
      Xgh[hc * 8192 + (size_t)r * 128 + col] = __float2bfloat16(qtv);
    }
  }
}

// ---------------- dual-role: chunk scan (blocks 0-127, XCD-swizzled) + gate GEMM (128-383) ----------------
#define STP 136
#define UTP 40

struct ChunkOps {
  bf16x8 ah[4];
  bf16x8 kah[2];
  f32x4 pvv[2];
  float pB[4];
};

__global__ __launch_bounds__(256) void kda_seq_gate(
    const __hip_bfloat16* __restrict__ Xgh, const __hip_bfloat16* __restrict__ KTh,
    const __hip_bfloat16* __restrict__ uvS, const __hip_bfloat16* __restrict__ olocS,
    const float* __restrict__ Pg, float* __restrict__ obuf,
    const __hip_bfloat16* __restrict__ g1b, const __hip_bfloat16* __restrict__ Wg2T,
    float* __restrict__ gatebuf)
{
  __shared__ char smem[65536];   // union: scan ~10KB | gemm 32KB
  const int tid = threadIdx.x;
  const int w = tid >> 6, lane = tid & 63, l15 = lane & 15, l4 = lane >> 4;

  if (blockIdx.x < 128) {
    // ---- scan path; h = bid & 15 so all 8 v-blocks of a head share one XCD's L2 (T1) ----
    __hip_bfloat16* STh = (__hip_bfloat16*)smem;
    __hip_bfloat16* STl = STh + 16 * STP;
    __hip_bfloat16* UTh = STl + 16 * STP;
    const int h = blockIdx.x & 15, vq = blockIdx.x >> 4;
    const int v0 = vq * 16;
    const int r0 = (w & 1) * 16 + l4 * 4;
    const int isO = (w < 2);

    for (int i = tid; i < 16 * STP; i += 256) {
      STh[i] = __float2bfloat16(0.f);
      STl[i] = __float2bfloat16(0.f);
    }
    __syncthreads();

    f32x4 S[2] = {};

    auto loadops = [&](ChunkOps& o, int c) {
      const size_t hc = (size_t)h * 64 + c;
      const __hip_bfloat16* xh = Xgh + hc * 8192 + (size_t)(w * 16 + l15) * 128 + l4 * 8;
#pragma unroll
      for (int kk = 0; kk < 4; ++kk) o.ah[kk] = *(const bf16x8*)(xh + kk * 32);
      const __hip_bfloat16* pb = (isO ? olocS : uvS) + (size_t)(c * 32 + r0) * 2048 + h * 128 + v0 + l15;
#pragma unroll
      for (int r = 0; r < 4; ++r) o.pB[r] = __bfloat162float(pb[(size_t)r * 2048]);
#pragma unroll
      for (int mi = 0; mi < 2; ++mi) {
        const int kd = (w * 2 + mi) * 16;
        o.kah[mi] = *(const bf16x8*)(KTh + hc * 4096 + (size_t)(kd + l15) * 32 + l4 * 8);
        o.pvv[mi] = *(const f32x4*)(Pg + hc * 128 + kd + l4 * 4);
      }
    };

    auto body = [&](ChunkOps& o, int c) {
      f32x4 Y = {};
#pragma unroll
      for (int kk = 0; kk < 4; ++kk) {
        const int so = l15 * STP + kk * 32 + l4 * 8;
        bf16x8 bh = *(const bf16x8*)(STh + so);
        bf16x8 bl = *(const bf16x8*)(STl + so);
        Y = __builtin_amdgcn_mfma_f32_16x16x32_bf16(o.ah[kk], bh, Y, 0, 0, 0);
        Y = __builtin_amdgcn_mfma_f32_16x16x32_bf16(o.ah[kk], bl, Y, 0, 0, 0);
      }

      if (isO) {
        size_t ob = (size_t)(c * 32 + r0) * 2048 + h * 128 + v0 + l15;
#pragma unroll
        for (int r = 0; r < 4; ++r)
          obuf[ob + (size_t)r * 2048] = Y[r] + o.pB[r];
      } else {
        union { __hip_bfloat16 b[4]; unsigned long long u; } uh;
#pragma unroll
        for (int r = 0; r < 4; ++r)
          uh.b[r] = __float2bfloat16(o.pB[r] - Y[r]);
        *(unsigned long long*)(UTh + l15 * UTP + r0) = uh.u;
      }
      __syncthreads();

#pragma unroll
      for (int mi = 0; mi < 2; ++mi) S[mi] *= o.pvv[mi];
      {
        bf16x8 ubh = *(const bf16x8*)(UTh + l15 * UTP + l4 * 8);
#pragma unroll
        for (int mi = 0; mi < 2; ++mi)
          S[mi] = __builtin_amdgcn_mfma_f32_16x16x32_bf16(o.kah[mi], ubh, S[mi], 0, 0, 0);
      }

#pragma unroll
      for (int mi = 0; mi < 2; ++mi) {
        const int kd0 = (w * 2 + mi) * 16 + l4 * 4;
        union { __hip_bfloat16 b[4]; unsigned long long u; } sh, sl;
#pragma unroll
        for (int r = 0; r < 4; ++r) {
          __hip_bfloat16 hh = __float2bfloat16(S[mi][r]);
          sh.b[r] = hh;
          sl.b[r] = __float2bfloat16(S[mi][r] - __bfloat162float(hh));
        }
        *(unsigned long long*)(STh + l15 * STP + kd0) = sh.u;
        *(unsigned long long*)(STl + l15 * STP + kd0) = sl.u;
      }
      __syncthreads();
    };

    ChunkOps A_, B_;
    loadops(A_, 0);
    for (int c = 0; c < 64; c += 2) {
      loadops(B_, c + 1);
      body(A_, c);
      if (c + 2 < 64) loadops(A_, c + 2);
      body(B_, c + 1);
    }
  } else {
    // ---- gate GEMM path: gatebuf[2048][2048] = g1b(lda 256) @ Wg2T(ldb 128), K=128 ----
    __hip_bfloat16* As = (__hip_bfloat16*)smem;
    __hip_bfloat16* Bs = As + BM * BKK;
    const int b2 = blockIdx.x - 128;
    const int m0 = (b2 >> 4) * BM, n0 = (b2 & 15) * BN;
    const int wm = w >> 1, wn = w & 1;

    f32x4 acc[4][4] = {};

    for (int k0 = 0; k0 < 128; k0 += BKK) {
#pragma unroll
      for (int i = 0; i < 4; ++i) {
        const int c = (w * 4 + i) * 64 + lane;
        const int row = c >> 3;
        const int colb = (c & 7) * 8;
        __builtin_amdgcn_global_load_lds(
            (const __attribute__((address_space(1))) void*)(g1b + (size_t)(m0 + row) * 256 + k0 + colb),
            (__attribute__((address_space(3))) void*)(As + (size_t)c * 8), 16, 0, 0);
        __builtin_amdgcn_global_load_lds(
            (const __attribute__((address_space(1))) void*)(Wg2T + (size_t)(n0 + row) * 128 + k0 + colb),
            (__attribute__((address_space(3))) void*)(Bs + (size_t)c * 8), 16, 0, 0);
      }
      __syncthreads();
#pragma unroll
      for (int kk = 0; kk < BKK; kk += 32) {
        bf16x8 af[4], bfv[4];
#pragma unroll
        for (int mi = 0; mi < 4; ++mi)
          af[mi] = *(const bf16x8*)(As + (wm * 64 + mi * 16 + l15) * BKK + kk + l4 * 8);
#pragma unroll
        for (int ni = 0; ni < 4; ++ni)
          bfv[ni] = *(const bf16x8*)(Bs + (wn * 64 + ni * 16 + l15) * BKK + kk + l4 * 8);
#pragma unroll
        for (int mi = 0; mi < 4; ++mi)
#pragma unroll
          for (int ni = 0; ni < 4; ++ni)
            acc[mi][ni] = __builtin_amdgcn_mfma_f32_16x16x32_bf16(af[mi], bfv[ni], acc[mi][ni], 0, 0, 0);
      }
      __syncthreads();
    }

#pragma unroll
    for (int mi = 0; mi < 4; ++mi)
#pragma unroll
      for (int ni = 0; ni < 4; ++ni) {
        const int row = m0 + wm * 64 + mi * 16 + l4 * 4;
        const int col = n0 + wn * 64 + ni * 16 + l15;
#pragma unroll
        for (int r = 0; r < 4; ++r)
          gatebuf[(size_t)(row + r) * 2048 + col] = acc[mi][ni][r];
      }
  }
}

// ---------------- sigmoid-gated RMSNorm -> bf16 ----------------
__global__ __launch_bounds__(256) void rmsgate_kernel(
    const float* __restrict__ o, const float* __restrict__ gate,
    const float* __restrict__ bg2, const float* __restrict__ norm_w,
    __hip_bfloat16* __restrict__ og)
{
  int row = blockIdx.x * 4 + (threadIdx.x >> 6);   // s*16 + h
  int lane = threadIdx.x & 63;
  int s = row >> 4, h = row & 15;
  int j = lane * 2;
  const float* p = o + (size_t)row * 128 + j;
  f32x2 v = *(const f32x2*)p;
  float ss = v.x * v.x + v.y * v.y;
#pragma unroll
  for (int off = 32; off > 0; off >>= 1) ss += __shfl_xor(ss, off);
  float rs = rsqrtf(ss * (1.f / 128.f) + 1e-6f);
  int c = h * 128 + j;
  float g0 = gate[(size_t)s * 2048 + c] + bg2[c];
  float g1 = gate[(size_t)s * 2048 + c + 1] + bg2[c + 1];
  float o0 = v.x * rs * norm_w[j] * (1.f / (1.f + expf(-g0)));
  float o1 = v.y * rs * norm_w[j + 1] * (1.f / (1.f + expf(-g1)));
  union { __hip_bfloat16 b[2]; unsigned int u; } pk2;
  pk2.b[0] = __float2bfloat16(o0);
  pk2.b[1] = __float2bfloat16(o1);
  *(unsigned int*)((char*)og + ((size_t)s * 2048 + c) * 2) = pk2.u;
}

// =====================================================================
extern "C" void kernel_launch(void* const* d_in, const int* in_sizes, int n_in,
                              void* d_out, int out_size, void* d_ws, size_t ws_size,
                              hipStream_t stream)
{
  const float* x      = (const float*)d_in[0];
  const float* ve     = (const float*)d_in[1];
  const float* lam    = (const float*)d_in[2];
  const float* Wq     = (const float*)d_in[3];
  const float* Wk     = (const float*)d_in[4];
  const float* Wv     = (const float*)d_in[5];
  const float* cwq    = (const float*)d_in[6];
  const float* cwk    = (const float*)d_in[7];
  const float* cwv    = (const float*)d_in[8];
  const float* Wf1    = (const float*)d_in[9];
  const float* Wf2    = (const float*)d_in[10];
  const float* Wb     = (const float*)d_in[11];
  const float* A_log  = (const float*)d_in[12];
  const float* dtb    = (const float*)d_in[13];
  const float* Wg1    = (const float*)d_in[14];
  const float* Wg2    = (const float*)d_in[15];
  const float* bg2    = (const float*)d_in[16];
  const float* norm_w = (const float*)d_in[17];
  const float* Wo     = (const float*)d_in[18];
  float* out = (float*)d_out;

  const size_t S2 = (size_t)2048 * 2048;

  char* p = (char*)d_ws;
  auto alloc = [&](size_t bytes) { char* r = p; p += (bytes + 255) & ~(size_t)255; return r; };

  __hip_bfloat16* xb     = (__hip_bfloat16*)alloc(S2 * 2);
  __hip_bfloat16* WoT    = (__hip_bfloat16*)alloc(S2 * 2);
  __hip_bfloat16* Wf2hT  = (__hip_bfloat16*)alloc(2048 * 128 * 2);
  __hip_bfloat16* Wf2lT  = (__hip_bfloat16*)alloc(2048 * 128 * 2);
  __hip_bfloat16* Wg2T   = (__hip_bfloat16*)alloc(2048 * 128 * 2);
  __hip_bfloat16* Wfg1hT = (__hip_bfloat16*)alloc((size_t)256 * 2048 * 2);
  __hip_bfloat16* Wfg1lT = (__hip_bfloat16*)alloc((size_t)256 * 2048 * 2);
  __hip_bfloat16* f1g1h  = (__hip_bfloat16*)alloc((size_t)2048 * 256 * 2);
  __hip_bfloat16* f1g1l  = (__hip_bfloat16*)alloc((size_t)2048 * 256 * 2);
  float* betaT = (float*)alloc((size_t)2048 * 16 * 4);
  __hip_bfloat16* qkvb = (__hip_bfloat16*)alloc(3 * S2 * 2);  // [2048][6144] bf16 (24MB)
  float* gbuf  = (float*)alloc(S2 * 4);
  float* gatebuf = (float*)alloc(S2 * 4);
  // uv/oloc payloads are bf16 (8MB used each) but keep 16MB allocs for the WqkvT/xlo overlays
  __hip_bfloat16* uvS   = (__hip_bfloat16*)alloc(S2 * 4);
  __hip_bfloat16* olocS = (__hip_bfloat16*)alloc(S2 * 4);
  __hip_bfloat16* Xgh = (__hip_bfloat16*)alloc(S2 * 4);   // 16MB: 1024 hc x 64 rows x 128 cols bf16
  __hip_bfloat16* KTh = (__hip_bfloat16*)alloc(S2 * 2);   // 8MB: 1024 hc x 128 x 32 bf16
  float* Pg    = (float*)alloc((size_t)1024 * 128 * 4);

  // overlays (timeline-checked):
  __hip_bfloat16* WqkvT = (__hip_bfloat16*)uvS;
  __hip_bfloat16* xlo = (__hip_bfloat16*)((char*)olocS + S2 * 2);
  float* fpart = (float*)Xgh;
  float* obuf  = gbuf;                           // gbuf dead after kda_pref
  __hip_bfloat16* og = (__hip_bfloat16*)qkvb;    // qkvb dead after kda_pref; og = first 8MB

  // 1. merged prep: all weight transposes + x split-cast (one launch)
  prep_all_kernel<<<21504, 256, 0, stream>>>(x, xb, xlo, Wq, Wk, Wv, Wo, WqkvT, WoT,
                                             Wf1, Wg1, Wfg1hT, Wfg1lT,
                                             Wf2, Wg2, Wf2hT, Wf2lT, Wg2T);

  // 2. merged QKV projection via 6-phase 256x192 GEMM (grid 256 = full CU fill) -> bf16 qkv
  gemm_bt192<<<dim3(32, 8), 512, 0, stream>>>(xb, WqkvT, qkvb, 6144, 2048, 2048, 32);

  // 3. merged f1|g1 stage (split-K z=8, 3-pass split precision; g1 half skips zero Bl pass)
  gemm_btsplit<<<dim3(2, 16, 8), 256, 0, stream>>>(xb, xlo, Wfg1hT, Wfg1lT, fpart,
                                                   2048, 256, 2048, 2048, 256, 128);
  reduce8_beta_kernel<<<640, 256, 0, stream>>>(fpart, f1g1h, f1g1l, (size_t)2048 * 256,
                                               x, Wb, betaT);

  // 4. f-path second stage: g = f1 @ Wf2 (split, full 3-pass)
  gemm_btsplit<<<dim3(16, 16), 256, 0, stream>>>(f1g1h, f1g1l, Wf2hT, Wf2lT, gbuf,
                                                 2048, 2048, 256, 128, 128, 1 << 30);

  // 5. fused prep + chunk-local precompute (reads bf16 qkv; writes bf16 uv/oloc)
  kda_pref<<<1024, 256, 0, stream>>>(qkvb, ve, lam, cwq, cwk, cwv, gbuf, dtb, A_log, betaT,
                                     Xgh, KTh, uvS, olocS, Pg);

  // 6. dual-role: chunk scan (128 blocks, XCD-swizzled) + gate GEMM (256 blocks) in one launch
  kda_seq_gate<<<384, 256, 0, stream>>>(Xgh, KTh, uvS, olocS, Pg, obuf,
                                        f1g1h + 128, Wg2T, gatebuf);

  // 7. gated rmsnorm -> bf16 (og aliases qkvb[0:8MB])
  rmsgate_kernel<<<8192, 256, 0, stream>>>(obuf, gatebuf, bg2, norm_w, og);

  // 8. output projection
  gemm_bt<<<dim3(16, 16), 256, 0, stream>>>(og, WoT, out, 2048, 2048, 2048, 2048, 2048, 0);
}

// Round 21
// 324.880 us; speedup vs baseline: 1.0221x; 1.0221x over previous
//
#include <hip/hip_runtime.h>
#include <hip/hip_bf16.h>
#include <stdint.h>
#include <stddef.h>

#define SEQL 2048
#define DIMSZ 2048
#define HN 16
#define DKD 128
#define DVD 128
#define QSCALE 0.08838834764831843f   // 128^-0.5

typedef __attribute__((ext_vector_type(4))) float f32x4;
typedef __attribute__((ext_vector_type(2))) float f32x2;
typedef __attribute__((ext_vector_type(8))) short bf16x8;

__device__ __forceinline__ float sigmoid_f(float x) { return 1.f / (1.f + __expf(-x)); }
__device__ __forceinline__ float bf2f(short s) {
  union { float f; unsigned int u; } t; t.u = ((unsigned int)(unsigned short)s) << 16; return t.f;
}

// ---------------- bf16 GEMM: C[M,N] (f32) = A[M,K]bf16 @ Bt[N,K]bf16 ----------------
#define BM 128
#define BN 128
#define BKK 64

__global__ __launch_bounds__(256) void gemm_bt(
    const __hip_bfloat16* __restrict__ A, const __hip_bfloat16* __restrict__ B,
    float* __restrict__ C, int M, int N, int lda, int ldb, int klen, int accum)
{
  __shared__ __hip_bfloat16 As[BM * BKK];
  __shared__ __hip_bfloat16 Bs[BN * BKK];
  const int tid = threadIdx.x;
  const int lane = tid & 63;
  const int w = tid >> 6;
  const int wm = w >> 1, wn = w & 1;            // 2x2 wave grid, 64x64 each
  const int m0 = blockIdx.y * BM, n0 = blockIdx.x * BN;
  const int l15 = lane & 15, l4 = lane >> 4;
  const int kbase = blockIdx.z * klen;

  f32x4 acc[4][4] = {};

  for (int k0 = kbase; k0 < kbase + klen; k0 += BKK) {
#pragma unroll
    for (int i = 0; i < 4; ++i) {
      const int c = (w * 4 + i) * 64 + lane;     // chunk id, 16B each; 8 chunks/row
      const int row = c >> 3;
      const int colb = (c & 7) * 8;
      __builtin_amdgcn_global_load_lds(
          (const __attribute__((address_space(1))) void*)(A + (size_t)(m0 + row) * lda + k0 + colb),
          (__attribute__((address_space(3))) void*)(As + (size_t)c * 8), 16, 0, 0);
      __builtin_amdgcn_global_load_lds(
          (const __attribute__((address_space(1))) void*)(B + (size_t)(n0 + row) * ldb + k0 + colb),
          (__attribute__((address_space(3))) void*)(Bs + (size_t)c * 8), 16, 0, 0);
    }
    __syncthreads();
#pragma unroll
    for (int kk = 0; kk < BKK; kk += 32) {
      bf16x8 af[4], bfv[4];
#pragma unroll
      for (int mi = 0; mi < 4; ++mi)
        af[mi] = *(const bf16x8*)(As + (wm * 64 + mi * 16 + l15) * BKK + kk + l4 * 8);
#pragma unroll
      for (int ni = 0; ni < 4; ++ni)
        bfv[ni] = *(const bf16x8*)(Bs + (wn * 64 + ni * 16 + l15) * BKK + kk + l4 * 8);
#pragma unroll
      for (int mi = 0; mi < 4; ++mi)
#pragma unroll
        for (int ni = 0; ni < 4; ++ni)
          acc[mi][ni] = __builtin_amdgcn_mfma_f32_16x16x32_bf16(af[mi], bfv[ni], acc[mi][ni], 0, 0, 0);
    }
    __syncthreads();
  }

  float* Cz = C + (size_t)blockIdx.z * M * N;
#pragma unroll
  for (int mi = 0; mi < 4; ++mi) {
#pragma unroll
    for (int ni = 0; ni < 4; ++ni) {
      const int row = m0 + wm * 64 + mi * 16 + l4 * 4;
      const int col = n0 + wn * 64 + ni * 16 + l15;
#pragma unroll
      for (int r = 0; r < 4; ++r) {
        size_t idx = (size_t)(row + r) * N + col;
        if (accum) Cz[idx] += acc[mi][ni][r];
        else Cz[idx] = acc[mi][ni][r];
      }
    }
  }
}

// ---------------- 256x192 6-phase GEMM (T2+T3+T4+T5), bf16 out; grid fills 256 CUs ----------------
__global__ __launch_bounds__(512, 1) void gemm_bt192(
    const __hip_bfloat16* __restrict__ A, const __hip_bfloat16* __restrict__ B,
    __hip_bfloat16* __restrict__ Cb, int N, int lda, int ldb, int NT)
{
  __shared__ __hip_bfloat16 lds[57344];   // 112 KiB
  const int tid = threadIdx.x;
  const int w = tid >> 6, lane = tid & 63;
  const int wm = w >> 2, wn = w & 3;
  const int l15 = lane & 15, l4 = lane >> 4;
  const int m0 = blockIdx.y * 256, n0 = blockIdx.x * 192;

  f32x4 acc[8][3] = {};
  bf16x8 a[4][2], b[2];

  auto stage_a = [&](int half, int t1) {
    const int buf = t1 & 1;
    const int k0n = ((t1 < NT) ? t1 : 0) * 64;
#pragma unroll
    for (int i = 0; i < 2; ++i) {
      const int c = i * 512 + tid;           // 1024 chunks per half
      const int l = half * 128 + (c >> 3);
      const int kcs = (c & 7) ^ (l & 7);
      const int grow = ((l >> 6) & 1) * 128 + (l >> 7) * 64 + (l & 63);
      __builtin_amdgcn_global_load_lds(
          (const __attribute__((address_space(1))) void*)(A + (size_t)(m0 + grow) * lda + k0n + kcs * 8),
          (__attribute__((address_space(3))) void*)(lds + (size_t)buf * 28672 + half * 8192 + (size_t)c * 8),
          16, 0, 0);
    }
  };
  auto stage_b = [&](int j, int t1) {
    const int buf = t1 & 1;
    const int k0n = ((t1 < NT) ? t1 : 0) * 64;
    const int c = tid;                       // 512 chunks per third
    const int l = j * 64 + (c >> 3);
    const int kcs = (c & 7) ^ (l & 7);
    __builtin_amdgcn_global_load_lds(
        (const __attribute__((address_space(1))) void*)(B + (size_t)(n0 + l) * ldb + k0n + kcs * 8),
        (__attribute__((address_space(3))) void*)(lds + (size_t)buf * 28672 + 16384 + j * 4096 + (size_t)c * 8),
        16, 0, 0);
  };

  auto phase = [&](size_t cb, int MQ, int NQ, bool needA) {
    if (needA) {
#pragma unroll
      for (int m2 = 0; m2 < 4; ++m2)
#pragma unroll
        for (int ks = 0; ks < 2; ++ks) {
          const int la = MQ * 128 + wm * 64 + m2 * 16 + l15;
          const int kc = ks * 4 + l4;
          a[m2][ks] = *(const bf16x8*)(lds + cb + la * 64 + (kc ^ (la & 7)) * 8);
        }
    }
#pragma unroll
    for (int ks = 0; ks < 2; ++ks) {
      const int lb = NQ * 64 + wn * 16 + l15;
      const int kc = ks * 4 + l4;
      b[ks] = *(const bf16x8*)(lds + cb + 16384 + lb * 64 + (kc ^ (lb & 7)) * 8);
    }
    __builtin_amdgcn_s_setprio(1);
#pragma unroll
    for (int m2 = 0; m2 < 4; ++m2)
#pragma unroll
      for (int ks = 0; ks < 2; ++ks)
        acc[MQ * 4 + m2][NQ] = __builtin_amdgcn_mfma_f32_16x16x32_bf16(
            a[m2][ks], b[ks], acc[MQ * 4 + m2][NQ], 0, 0, 0);
    __builtin_amdgcn_s_setprio(0);
  };

  stage_a(0, 0); stage_a(1, 0); stage_b(0, 0); stage_b(1, 0); stage_b(2, 0);

  for (int t = 0; t < NT; ++t) {
    const size_t cb = (size_t)(t & 1) * 28672;
    stage_a(0, t + 1);
    asm volatile("s_waitcnt vmcnt(4)" ::: "memory");
    __builtin_amdgcn_s_barrier();
    __builtin_amdgcn_sched_barrier(0);
    phase(cb, 0, 0, true);
    __builtin_amdgcn_s_barrier();
    stage_a(1, t + 1);
    asm volatile("s_waitcnt vmcnt(5)" ::: "memory");
    __builtin_amdgcn_s_barrier();
    __builtin_amdgcn_sched_barrier(0);
    phase(cb, 0, 1, false);
    __builtin_amdgcn_s_barrier();
    stage_b(0, t + 1);
    asm volatile("s_waitcnt vmcnt(5)" ::: "memory");
    __builtin_amdgcn_s_barrier();
    __builtin_amdgcn_sched_barrier(0);
    phase(cb, 0, 2, false);
    __builtin_amdgcn_s_barrier();
    stage_b(1, t + 1);
    __builtin_amdgcn_s_barrier();
    __builtin_amdgcn_sched_barrier(0);
    phase(cb, 1, 0, true);
    __builtin_amdgcn_s_barrier();
    stage_b(2, t + 1);
    __builtin_amdgcn_s_barrier();
    __builtin_amdgcn_sched_barrier(0);
    phase(cb, 1, 1, false);
    __builtin_amdgcn_s_barrier();
    __builtin_amdgcn_s_barrier();
    __builtin_amdgcn_sched_barrier(0);
    phase(cb, 1, 2, false);
    __builtin_amdgcn_s_barrier();
  }
  asm volatile("s_waitcnt vmcnt(0)" ::: "memory");

#pragma unroll
  for (int mi = 0; mi < 8; ++mi)
#pragma unroll
    for (int nq = 0; nq < 3; ++nq) {
      const int row = m0 + wm * 128 + mi * 16 + l4 * 4;
      const int col = n0 + nq * 64 + wn * 16 + l15;
#pragma unroll
      for (int r = 0; r < 4; ++r)
        Cb[(size_t)(row + r) * N + col] = __float2bfloat16(acc[mi][nq][r]);
    }
}

// ---------------- fused split-precision GEMM: C = Ah@Bh + Ah@Bl + Al@Bh ----------------
__global__ __launch_bounds__(256) void gemm_btsplit(
    const __hip_bfloat16* __restrict__ Ah, const __hip_bfloat16* __restrict__ Al,
    const __hip_bfloat16* __restrict__ Bh, const __hip_bfloat16* __restrict__ Bl,
    float* __restrict__ C, int M, int N, int lda, int ldb, int klen)
{
  __shared__ __hip_bfloat16 Ash[BM * BKK];
  __shared__ __hip_bfloat16 Asl[BM * BKK];
  __shared__ __hip_bfloat16 Bsh[BN * BKK];
  __shared__ __hip_bfloat16 Bsl[BN * BKK];
  const int tid = threadIdx.x;
  const int lane = tid & 63;
  const int w = tid >> 6;
  const int wm = w >> 1, wn = w & 1;
  const int m0 = blockIdx.y * BM, n0 = blockIdx.x * BN;
  const int l15 = lane & 15, l4 = lane >> 4;
  const int kbase = blockIdx.z * klen;

  f32x4 acc[4][4] = {};

  for (int k0 = kbase; k0 < kbase + klen; k0 += BKK) {
#pragma unroll
    for (int i = 0; i < 4; ++i) {
      const int c = (w * 4 + i) * 64 + lane;
      const int row = c >> 3;
      const int colb = (c & 7) * 8;
      const size_t go = (size_t)(m0 + row) * lda + k0 + colb;
      const size_t gn = (size_t)(n0 + row) * ldb + k0 + colb;
      __builtin_amdgcn_global_load_lds(
          (const __attribute__((address_space(1))) void*)(Ah + go),
          (__attribute__((address_space(3))) void*)(Ash + (size_t)c * 8), 16, 0, 0);
      __builtin_amdgcn_global_load_lds(
          (const __attribute__((address_space(1))) void*)(Al + go),
          (__attribute__((address_space(3))) void*)(Asl + (size_t)c * 8), 16, 0, 0);
      __builtin_amdgcn_global_load_lds(
          (const __attribute__((address_space(1))) void*)(Bh + gn),
          (__attribute__((address_space(3))) void*)(Bsh + (size_t)c * 8), 16, 0, 0);
      __builtin_amdgcn_global_load_lds(
          (const __attribute__((address_space(1))) void*)(Bl + gn),
          (__attribute__((address_space(3))) void*)(Bsl + (size_t)c * 8), 16, 0, 0);
    }
    __syncthreads();
#pragma unroll
    for (int kk = 0; kk < BKK; kk += 32) {
      bf16x8 afh[4], afl[4], bfh[4], bfl[4];
#pragma unroll
      for (int mi = 0; mi < 4; ++mi) {
        const int ao = (wm * 64 + mi * 16 + l15) * BKK + kk + l4 * 8;
        afh[mi] = *(const bf16x8*)(Ash + ao);
        afl[mi] = *(const bf16x8*)(Asl + ao);
      }
#pragma unroll
      for (int ni = 0; ni < 4; ++ni) {
        const int bo = (wn * 64 + ni * 16 + l15) * BKK + kk + l4 * 8;
        bfh[ni] = *(const bf16x8*)(Bsh + bo);
        bfl[ni] = *(const bf16x8*)(Bsl + bo);
      }
#pragma unroll
      for (int mi = 0; mi < 4; ++mi)
#pragma unroll
        for (int ni = 0; ni < 4; ++ni) {
          acc[mi][ni] = __builtin_amdgcn_mfma_f32_16x16x32_bf16(afh[mi], bfh[ni], acc[mi][ni], 0, 0, 0);
          acc[mi][ni] = __builtin_amdgcn_mfma_f32_16x16x32_bf16(afh[mi], bfl[ni], acc[mi][ni], 0, 0, 0);
          acc[mi][ni] = __builtin_amdgcn_mfma_f32_16x16x32_bf16(afl[mi], bfh[ni], acc[mi][ni], 0, 0, 0);
        }
    }
    __syncthreads();
  }

  float* Cz = C + (size_t)blockIdx.z * M * N;
#pragma unroll
  for (int mi = 0; mi < 4; ++mi) {
#pragma unroll
    for (int ni = 0; ni < 4; ++ni) {
      const int row = m0 + wm * 64 + mi * 16 + l4 * 4;
      const int col = n0 + wn * 64 + ni * 16 + l15;
#pragma unroll
      for (int r = 0; r < 4; ++r)
        Cz[(size_t)(row + r) * N + col] = acc[mi][ni][r];
    }
  }
}

// ---------------- merged weight transposes + x split-cast (one launch) ----------------
__global__ __launch_bounds__(256) void prep_all_kernel(
    const float* __restrict__ x, __hip_bfloat16* __restrict__ xb, __hip_bfloat16* __restrict__ xlo,
    const float* __restrict__ Wq, const float* __restrict__ Wk,
    const float* __restrict__ Wv, const float* __restrict__ Wo,
    __hip_bfloat16* __restrict__ WqkvT, __hip_bfloat16* __restrict__ WoT,
    const float* __restrict__ Wf1, const float* __restrict__ Wg1,
    __hip_bfloat16* __restrict__ fg1h, __hip_bfloat16* __restrict__ fg1l,
    const float* __restrict__ Wf2, const float* __restrict__ Wg2,
    __hip_bfloat16* __restrict__ f2h, __hip_bfloat16* __restrict__ f2l,
    __hip_bfloat16* __restrict__ g2h)
{
  __shared__ float tile[32][33];
  const int bid = blockIdx.x;
  const int tid = threadIdx.x;
  const int tc = tid & 31, tr = tid >> 5;

  if (bid < 16384) {
    const int z = bid >> 12, rem = bid & 4095;
    const int c0 = (rem & 63) * 32, r0 = (rem >> 6) * 32;
    const float* in = (z == 0) ? Wq : (z == 1) ? Wk : (z == 2) ? Wv : Wo;
    __hip_bfloat16* outT = (z < 3) ? (WqkvT + (size_t)z * 2048 * 2048) : WoT;
#pragma unroll
    for (int i = 0; i < 4; ++i)
      tile[tr + i * 8][tc] = in[(size_t)(r0 + tr + i * 8) * 2048 + c0 + tc];
    __syncthreads();
#pragma unroll
    for (int i = 0; i < 4; ++i)
      outT[(size_t)(c0 + tr + i * 8) * 2048 + r0 + tc] = __float2bfloat16(tile[tc][tr + i * 8]);
  } else if (bid < 16896) {
    const int rem = bid - 16384;
    const int z = rem >> 8, within = rem & 255;
    const int c0 = (within & 3) * 32, r0 = (within >> 2) * 32;   // c over 128, r over 2048
    const float* in = z ? Wg1 : Wf1;
    const size_t base = (size_t)z * 128 * 2048;
#pragma unroll
    for (int i = 0; i < 4; ++i)
      tile[tr + i * 8][tc] = in[(size_t)(r0 + tr + i * 8) * 128 + c0 + tc];
    __syncthreads();
#pragma unroll
    for (int i = 0; i < 4; ++i) {
      float val = tile[tc][tr + i * 8];
      __hip_bfloat16 h = __float2bfloat16(val);
      size_t oi = base + (size_t)(c0 + tr + i * 8) * 2048 + r0 + tc;
      fg1h[oi] = h;
      fg1l[oi] = z ? __float2bfloat16(0.f) : __float2bfloat16(val - __bfloat162float(h));
    }
  } else if (bid < 17408) {
    const int rem = bid - 16896;
    const int z = rem >> 8, within = rem & 255;
    const int c0 = (within & 63) * 32, r0 = (within >> 6) * 32;  // c over 2048, r over 128
    const float* in = z ? Wg2 : Wf2;
#pragma unroll
    for (int i = 0; i < 4; ++i)
      tile[tr + i * 8][tc] = in[(size_t)(r0 + tr + i * 8) * 2048 + c0 + tc];
    __syncthreads();
#pragma unroll
    for (int i = 0; i < 4; ++i) {
      float val = tile[tc][tr + i * 8];
      __hip_bfloat16 h = __float2bfloat16(val);
      size_t oi = (size_t)(c0 + tr + i * 8) * 128 + r0 + tc;
      if (z == 0) { f2h[oi] = h; f2l[oi] = __float2bfloat16(val - __bfloat162float(h)); }
      else g2h[oi] = h;
    }
  } else {
    const int idx = (bid - 17408) * 256 + tid;   // exactly covers S2/4
    f32x4 v = *(const f32x4*)(x + (size_t)idx * 4);
    union { __hip_bfloat16 b[4]; unsigned long long u; } ph, pl;
#pragma unroll
    for (int j = 0; j < 4; ++j) {
      float f = v[j];
      __hip_bfloat16 hh = __float2bfloat16(f);
      ph.b[j] = hh;
      pl.b[j] = __float2bfloat16(f - __bfloat162float(hh));
    }
    *(unsigned long long*)((char*)xb + (size_t)idx * 8) = ph.u;
    *(unsigned long long*)((char*)xlo + (size_t)idx * 8) = pl.u;
  }
}

// ---------------- split-K reduce (8 partials) -> bf16 hi+lo, fused with beta ----------------
__global__ __launch_bounds__(256) void reduce8_beta_kernel(
    const float* __restrict__ part, __hip_bfloat16* __restrict__ hi,
    __hip_bfloat16* __restrict__ lo, size_t chunk,
    const float* __restrict__ x, const float* __restrict__ Wb, float* __restrict__ betaT)
{
  const int tid = threadIdx.x;
  if (blockIdx.x < 512) {
    int idx = blockIdx.x * 256 + tid;
    f32x4 a = *(const f32x4*)(part + (size_t)idx * 4);
#pragma unroll
    for (int z = 1; z < 8; ++z) {
      f32x4 b = *(const f32x4*)(part + z * chunk + (size_t)idx * 4);
      a.x += b.x; a.y += b.y; a.z += b.z; a.w += b.w;
    }
    union { __hip_bfloat16 b[4]; unsigned long long u; } ph, pl;
#pragma unroll
    for (int j = 0; j < 4; ++j) {
      float f = a[j];
      __hip_bfloat16 hh = __float2bfloat16(f);
      ph.b[j] = hh;
      pl.b[j] = __float2bfloat16(f - __bfloat162float(hh));
    }
    *(unsigned long long*)((char*)hi + (size_t)idx * 8) = ph.u;
    *(unsigned long long*)((char*)lo + (size_t)idx * 8) = pl.u;
  } else {
    int idx = (blockIdx.x - 512) * 256 + tid;    // 0..32767
    int s = idx >> 4, h = idx & 15;
    const float* xr = x + (size_t)s * DIMSZ;
    float acc = 0.f;
    for (int d = 0; d < DIMSZ; d += 4) {
      f32x4 xv = *(const f32x4*)(xr + d);
      acc = fmaf(xv.x, Wb[(size_t)(d + 0) * HN + h], acc);
      acc = fmaf(xv.y, Wb[(size_t)(d + 1) * HN + h], acc);
      acc = fmaf(xv.z, Wb[(size_t)(d + 2) * HN + h], acc);
      acc = fmaf(xv.w, Wb[(size_t)(d + 3) * HN + h], acc);
    }
    betaT[(size_t)h * SEQL + s] = 1.f / (1.f + expf(-acc));
  }
}

// ---------------- fused prep + chunk-local precompute (C=32); qkv in bf16 ----------------
#define SL20(r, d) ((r) * 160 + ((d) >> 4) * 20 + ((d) & 15))

__global__ __launch_bounds__(256) void kda_pref(
    const __hip_bfloat16* __restrict__ qkv, const float* __restrict__ ve,
    const float* __restrict__ lam,
    const float* __restrict__ cwq, const float* __restrict__ cwk, const float* __restrict__ cwv,
    const float* __restrict__ gbuf,
    const float* __restrict__ dtb, const float* __restrict__ A_log,
    const float* __restrict__ betaT,
    __hip_bfloat16* __restrict__ Xgh, __hip_bfloat16* __restrict__ KTh,
    float* __restrict__ uvS, float* __restrict__ olocS, float* __restrict__ Pg)
{
  __shared__ float GL2[32 * 160];
  __shared__ float kL2[32 * 160];
  __shared__ float qL2[32 * 132];
  __shared__ float vL2[32 * 128];
  __shared__ float ALB[32][33];      // lower: A; upper [i][t]: B[t][i] (i<t)
  __shared__ float Bdiag[32], betaL[32];
  __shared__ float csumW[4 * 128];

  const int bid = blockIdx.x;
  const int h = bid >> 6, cc = bid & 63;
  const int tid = threadIdx.x;
  const int w = tid >> 6, lane = tid & 63;
  const size_t hc = (size_t)h * 64 + cc;
  const float Aexp = __expf(A_log[h]);

  // ======== phase 1: conv + silu + mix + l2norm + glog ========
  {
    const int c = lane * 2;                 // col pair
    const int r0g = cc * 32 + w * 8;        // global row base for this wave
    const int cg = h * 128 + c;

    f32x4 wq0 = *(const f32x4*)(cwq + (size_t)cg * 4), wq1 = *(const f32x4*)(cwq + (size_t)(cg + 1) * 4);
    f32x4 wk0 = *(const f32x4*)(cwk + (size_t)cg * 4), wk1 = *(const f32x4*)(cwk + (size_t)(cg + 1) * 4);
    f32x4 wv0 = *(const f32x4*)(cwv + (size_t)cg * 4), wv1 = *(const f32x4*)(cwv + (size_t)(cg + 1) * 4);
    f32x2 dt2 = *(const f32x2*)(dtb + cg);
    const float l0 = lam[0], l1 = lam[1];

    f32x2 xqr[11], xkr[11], xvr[11];
#pragma unroll
    for (int i = 0; i < 11; ++i) {
      const int sr = r0g - 3 + i;
      if (sr >= 0) {
        const size_t ro = (size_t)sr * 6144 + cg;
        unsigned int uq = *(const unsigned int*)(qkv + ro);
        unsigned int uk = *(const unsigned int*)(qkv + 2048 + ro);
        unsigned int uv2 = *(const unsigned int*)(qkv + 4096 + ro);
        xqr[i].x = bf2f((short)uq);   xqr[i].y = bf2f((short)(uq >> 16));
        xkr[i].x = bf2f((short)uk);   xkr[i].y = bf2f((short)(uk >> 16));
        xvr[i].x = bf2f((short)uv2);  xvr[i].y = bf2f((short)(uv2 >> 16));
      } else {
        xqr[i].x = xqr[i].y = xkr[i].x = xkr[i].y = xvr[i].x = xvr[i].y = 0.f;
      }
    }

    float gl0[8], gl1[8];
#pragma unroll
    for (int i = 0; i < 8; ++i) {
      const int rr = r0g + i;
      const int lr = w * 8 + i;
      float aq0 = 0, aq1 = 0, ak0 = 0, ak1 = 0, av0 = 0, av1 = 0;
#pragma unroll
      for (int j = 0; j < 4; ++j) {
        aq0 = fmaf(xqr[i + j].x, wq0[j], aq0); aq1 = fmaf(xqr[i + j].y, wq1[j], aq1);
        ak0 = fmaf(xkr[i + j].x, wk0[j], ak0); ak1 = fmaf(xkr[i + j].y, wk1[j], ak1);
        av0 = fmaf(xvr[i + j].x, wv0[j], av0); av1 = fmaf(xvr[i + j].y, wv1[j], av1);
      }
      float yq0 = aq0 * sigmoid_f(aq0), yq1 = aq1 * sigmoid_f(aq1);
      float yk0 = ak0 * sigmoid_f(ak0), yk1 = ak1 * sigmoid_f(ak1);
      float yv0 = av0 * sigmoid_f(av0), yv1 = av1 * sigmoid_f(av1);

      f32x2 vev = *(const f32x2*)(ve + ((size_t)rr * HN + h) * 128 + c);
      float v0 = l0 * yv0 + l1 * vev.x;
      float v1 = l0 * yv1 + l1 * vev.y;

      float ssq = yq0 * yq0 + yq1 * yq1;
      float ssk = yk0 * yk0 + yk1 * yk1;
#pragma unroll
      for (int off = 32; off > 0; off >>= 1) {
        ssq += __shfl_xor(ssq, off);
        ssk += __shfl_xor(ssk, off);
      }
      float rq = rsqrtf(ssq + 1e-6f) * QSCALE;
      float rk = rsqrtf(ssk + 1e-6f);

      f32x2 kk; kk.x = yk0 * rk; kk.y = yk1 * rk;
      f32x2 qq; qq.x = yq0 * rq; qq.y = yq1 * rq;
      f32x2 vv; vv.x = v0; vv.y = v1;
      *(f32x2*)&kL2[SL20(lr, c)] = kk;
      *(f32x2*)&qL2[lr * 132 + c] = qq;
      *(f32x2*)&vL2[lr * 128 + c] = vv;

      f32x2 gv = *(const f32x2*)(gbuf + (size_t)rr * 2048 + cg);
      float g0 = gv.x + dt2.x, g1 = gv.y + dt2.y;
      float sp0 = (g0 > 20.f) ? g0 : __logf(1.f + __expf(g0));
      float sp1 = (g1 > 20.f) ? g1 : __logf(1.f + __expf(g1));
      gl0[i] = -Aexp * sp0;
      gl1[i] = -Aexp * sp1;
    }
    // per-wave cumsum
    {
      float r0 = 0.f, r1 = 0.f;
#pragma unroll
      for (int i = 0; i < 8; ++i) { r0 += gl0[i]; gl0[i] = r0; r1 += gl1[i]; gl1[i] = r1; }
      csumW[w * 128 + c] = r0;
      csumW[w * 128 + c + 1] = r1;
    }
    if (tid < 32) betaL[tid] = betaT[(size_t)h * SEQL + cc * 32 + tid];
    __syncthreads();
    // cross-wave prefix, write GL
    {
      float p0 = 0.f, p1 = 0.f;
      for (int wp = 0; wp < w; ++wp) { p0 += csumW[wp * 128 + c]; p1 += csumW[wp * 128 + c + 1]; }
#pragma unroll
      for (int i = 0; i < 8; ++i) {
        f32x2 gg; gg.x = gl0[i] + p0; gg.y = gl1[i] + p1;
        *(f32x2*)&GL2[SL20(w * 8 + i, c)] = gg;
      }
    }
  }
  __syncthreads();

  // ======== phase 2: rebased MFMA inter-blocks + scalar 8x8 triangles ========
  {
    const int m = lane & 15, quad = lane >> 4;
    // ---- MFMA job: w0=A16, w1=B16, w2=A8pack, w3=B8pack ----
    {
      const bool useQ = (w & 1);
      int tL, iR, ref;
      if (w < 2)      { tL = 16 + m; iR = m;     ref = 15; }
      else if (m < 8) { tL = 8 + m;  iR = m;     ref = 7;  }
      else            { tL = 16 + m; iR = 8 + m; ref = 23; }

      f32x4 accM = {};
#pragma unroll
      for (int kk = 0; kk < 4; ++kk) {
        const int d0 = kk * 32 + quad * 8;
        const int slb = (d0 >> 4) * 20 + (d0 & 15);
        f32x4 gL0 = *(const f32x4*)&GL2[tL * 160 + slb];
        f32x4 gL1 = *(const f32x4*)&GL2[tL * 160 + slb + 4];
        f32x4 gR0 = *(const f32x4*)&GL2[iR * 160 + slb];
        f32x4 gR1 = *(const f32x4*)&GL2[iR * 160 + slb + 4];
        f32x4 gF0 = *(const f32x4*)&GL2[ref * 160 + slb];
        f32x4 gF1 = *(const f32x4*)&GL2[ref * 160 + slb + 4];
        f32x4 kR0 = *(const f32x4*)&kL2[iR * 160 + slb];
        f32x4 kR1 = *(const f32x4*)&kL2[iR * 160 + slb + 4];
        f32x4 vL0, vL1;
        if (useQ) {
          vL0 = *(const f32x4*)&qL2[tL * 132 + d0];
          vL1 = *(const f32x4*)&qL2[tL * 132 + d0 + 4];
        } else {
          vL0 = *(const f32x4*)&kL2[tL * 160 + slb];
          vL1 = *(const f32x4*)&kL2[tL * 160 + slb + 4];
        }
        union { bf16x8 v; unsigned short u[8]; } lh, ll, rh, rl;
#pragma unroll
        for (int j = 0; j < 4; ++j) {
          float fl = vL0[j] * __expf(gL0[j] - gF0[j]);
          float fr = kR0[j] * __expf(gF0[j] - gR0[j]);
          __hip_bfloat16 h1 = __float2bfloat16(fl);
          __hip_bfloat16 h1l = __float2bfloat16(fl - __bfloat162float(h1));
          __hip_bfloat16 h2 = __float2bfloat16(fr);
          __hip_bfloat16 h2l = __float2bfloat16(fr - __bfloat162float(h2));
          lh.u[j] = *(const unsigned short*)&h1; ll.u[j] = *(const unsigned short*)&h1l;
          rh.u[j] = *(const unsigned short*)&h2; rl.u[j] = *(const unsigned short*)&h2l;
          float fl2 = vL1[j] * __expf(gL1[j] - gF1[j]);
          float fr2 = kR1[j] * __expf(gF1[j] - gR1[j]);
          __hip_bfloat16 h3 = __float2bfloat16(fl2);
          __hip_bfloat16 h3l = __float2bfloat16(fl2 - __bfloat162float(h3));
          __hip_bfloat16 h4 = __float2bfloat16(fr2);
          __hip_bfloat16 h4l = __float2bfloat16(fr2 - __bfloat162float(h4));
          lh.u[4 + j] = *(const unsigned short*)&h3; ll.u[4 + j] = *(const unsigned short*)&h3l;
          rh.u[4 + j] = *(const unsigned short*)&h4; rl.u[4 + j] = *(const unsigned short*)&h4l;
        }
        accM = __builtin_amdgcn_mfma_f32_16x16x32_bf16(lh.v, rh.v, accM, 0, 0, 0);
        accM = __builtin_amdgcn_mfma_f32_16x16x32_bf16(lh.v, rl.v, accM, 0, 0, 0);
        accM = __builtin_amdgcn_mfma_f32_16x16x32_bf16(ll.v, rh.v, accM, 0, 0, 0);
      }
#pragma unroll
      for (int r = 0; r < 4; ++r) {
        const int row = quad * 4 + r;
        const int col = m;
        if (w < 2) {
          if (useQ) ALB[col][16 + row] = accM[r];
          else      ALB[16 + row][col] = accM[r];
        } else if ((row < 8) == (col < 8)) {
          const int t = (row < 8) ? (8 + row) : (16 + row);
          const int i = (col < 8) ? col : (8 + col);
          if (useQ) ALB[i][t] = accM[r];
          else      ALB[t][i] = accM[r];
        }
      }
    }
    // ---- scalar 8x8 triangle T_w (rows [8w, 8w+8)) ----
    {
      const int tg = lane >> 3, s8 = lane & 7;
      const int base = w * 8;
      const int tt = base + tg;
      const int ds = s8 * 20;

      float Gt[16], kt[16], qt[16];
#pragma unroll
      for (int j = 0; j < 16; j += 4) {
        *(f32x4*)&Gt[j] = *(const f32x4*)&GL2[tt * 160 + ds + j];
        *(f32x4*)&kt[j] = *(const f32x4*)&kL2[tt * 160 + ds + j];
        *(f32x4*)&qt[j] = *(const f32x4*)&qL2[tt * 132 + s8 * 16 + j];
      }
      {
        float sA = 0.f, sB = 0.f;
#pragma unroll
        for (int j = 0; j < 16; ++j) { sA = fmaf(kt[j], kt[j], sA); sB = fmaf(qt[j], kt[j], sB); }
        sA += __shfl_xor(sA, 1); sA += __shfl_xor(sA, 2); sA += __shfl_xor(sA, 4);
        sB += __shfl_xor(sB, 1); sB += __shfl_xor(sB, 2); sB += __shfl_xor(sB, 4);
        if (s8 == 0) { ALB[tt][tt] = sA; Bdiag[tt] = sB; }
      }
      for (int i = base; i < base + 7; ++i) {
        if (i < tt) {
          float sA = 0.f, sB = 0.f;
#pragma unroll
          for (int jj = 0; jj < 4; ++jj) {
            f32x4 Gi = *(const f32x4*)&GL2[i * 160 + ds + jj * 4];
            f32x4 ki = *(const f32x4*)&kL2[i * 160 + ds + jj * 4];
#pragma unroll
            for (int u = 0; u < 4; ++u) {
              float e = __expf(Gt[jj * 4 + u] - Gi[u]);
              float kid = ki[u] * e;
              sA = fmaf(kt[jj * 4 + u], kid, sA);
              sB = fmaf(qt[jj * 4 + u], kid, sB);
            }
          }
          sA += __shfl_xor(sA, 1); sA += __shfl_xor(sA, 2); sA += __shfl_xor(sA, 4);
          sB += __shfl_xor(sB, 1); sB += __shfl_xor(sB, 2); sB += __shfl_xor(sB, 4);
          if (s8 == 0) { ALB[tt][i] = sA; ALB[i][tt] = sB; }
        }
      }
    }
  }
  __syncthreads();

  // ======== phase 3: KbarT + role-split substitution ========
  const int col = tid & 127, half = tid >> 7;
  const size_t rowbase = (size_t)(cc * 32) * 2048 + h * 128 + col;
  const int rbase = half * 16;
  {
    const float g31 = GL2[SL20(31, col)];
    size_t kb = hc * 4096 + (size_t)col * 32;
#pragma unroll
    for (int i = 0; i < 16; ++i) {
      int r = rbase + i;
      float kv = kL2[SL20(r, col)] * __expf(g31 - GL2[SL20(r, col)]);
      KTh[kb + r] = __float2bfloat16(kv);
    }
  }

  float expg[32];
#pragma unroll
  for (int r = 0; r < 32; ++r) expg[r] = __expf(GL2[SL20(r, col)]);

  if (half == 0) {
    // uv recurrence + oloc
    float uvr[32];
#pragma unroll
    for (int r = 0; r < 32; ++r) {
      float suv = 0.f;
#pragma unroll
      for (int j = 0; j < 32; ++j) {
        if (j < r) suv = fmaf(ALB[r][j], uvr[j], suv);
      }
      uvr[r] = betaL[r] * (vL2[r * 128 + col] - suv);
      uvS[rowbase + (size_t)r * 2048] = uvr[r];
    }
#pragma unroll
    for (int r = 0; r < 32; ++r) {
      float ol = Bdiag[r] * uvr[r];
#pragma unroll
      for (int j = 0; j < 32; ++j) {
        if (j < r) ol = fmaf(ALB[j][r], uvr[j], ol);
      }
      olocS[rowbase + (size_t)r * 2048] = ol;
    }
    Pg[hc * 128 + col] = expg[31];
  } else {
    // w recurrence + Qt
    float wr[32];
#pragma unroll
    for (int r = 0; r < 32; ++r) {
      float sw = 0.f;
#pragma unroll
      for (int j = 0; j < 32; ++j) {
        if (j < r) sw = fmaf(ALB[r][j], wr[j], sw);
      }
      wr[r] = betaL[r] * (kL2[SL20(r, col)] * expg[r] - sw);
      Xgh[hc * 8192 + (size_t)(32 + r) * 128 + col] = __float2bfloat16(wr[r]);
    }
#pragma unroll
    for (int r = 0; r < 32; ++r) {
      float qtv = qL2[r * 132 + col] * expg[r];
      qtv = fmaf(-Bdiag[r], wr[r], qtv);
#pragma unroll
      for (int j = 0; j < 32; ++j) {
        if (j < r) qtv = fmaf(-ALB[j][r], wr[j], qtv);
      }
      Xgh[hc * 8192 + (size_t)r * 128 + col] = __float2bfloat16(qtv);
    }
  }
}

// ---------------- dual-role: chunk scan (blocks 0-127, XCD-swizzled) + gate GEMM (128-383) ----------------
#define STP 136
#define UTP 40

struct ChunkOps {
  bf16x8 ah[4];
  bf16x8 kah[2];
  f32x4 pvv[2];
  float pB[4];
};

__global__ __launch_bounds__(256) void kda_seq_gate(
    const __hip_bfloat16* __restrict__ Xgh, const __hip_bfloat16* __restrict__ KTh,
    const float* __restrict__ uvS, const float* __restrict__ olocS,
    const float* __restrict__ Pg, float* __restrict__ obuf,
    const __hip_bfloat16* __restrict__ g1b, const __hip_bfloat16* __restrict__ Wg2T,
    float* __restrict__ gatebuf)
{
  __shared__ char smem[65536];   // union: scan ~10KB | gemm 32KB
  const int tid = threadIdx.x;
  const int w = tid >> 6, lane = tid & 63, l15 = lane & 15, l4 = lane >> 4;

  if (blockIdx.x < 128) {
    // ---- scan path; h = bid & 15 so all 8 v-blocks of a head share one XCD's L2 (T1) ----
    __hip_bfloat16* STh = (__hip_bfloat16*)smem;
    __hip_bfloat16* STl = STh + 16 * STP;
    __hip_bfloat16* UTh = STl + 16 * STP;
    const int h = blockIdx.x & 15, vq = blockIdx.x >> 4;
    const int v0 = vq * 16;
    const int r0 = (w & 1) * 16 + l4 * 4;
    const int isO = (w < 2);

    for (int i = tid; i < 16 * STP; i += 256) {
      STh[i] = __float2bfloat16(0.f);
      STl[i] = __float2bfloat16(0.f);
    }
    __syncthreads();

    f32x4 S[2] = {};

    auto loadops = [&](ChunkOps& o, int c) {
      const size_t hc = (size_t)h * 64 + c;
      const __hip_bfloat16* xh = Xgh + hc * 8192 + (size_t)(w * 16 + l15) * 128 + l4 * 8;
#pragma unroll
      for (int kk = 0; kk < 4; ++kk) o.ah[kk] = *(const bf16x8*)(xh + kk * 32);
      const float* pb = (isO ? olocS : uvS) + (size_t)(c * 32 + r0) * 2048 + h * 128 + v0 + l15;
#pragma unroll
      for (int r = 0; r < 4; ++r) o.pB[r] = pb[(size_t)r * 2048];
#pragma unroll
      for (int mi = 0; mi < 2; ++mi) {
        const int kd = (w * 2 + mi) * 16;
        o.kah[mi] = *(const bf16x8*)(KTh + hc * 4096 + (size_t)(kd + l15) * 32 + l4 * 8);
        o.pvv[mi] = *(const f32x4*)(Pg + hc * 128 + kd + l4 * 4);
      }
    };

    auto body = [&](ChunkOps& o, int c) {
      // 4 independent accumulators: dependent-MFMA chain 8L -> ~2L + add tree
      f32x4 Yp[4] = {};
#pragma unroll
      for (int kk = 0; kk < 4; ++kk) {
        const int so = l15 * STP + kk * 32 + l4 * 8;
        bf16x8 bh = *(const bf16x8*)(STh + so);
        bf16x8 bl = *(const bf16x8*)(STl + so);
        Yp[kk] = __builtin_amdgcn_mfma_f32_16x16x32_bf16(o.ah[kk], bh, Yp[kk], 0, 0, 0);
        Yp[kk] = __builtin_amdgcn_mfma_f32_16x16x32_bf16(o.ah[kk], bl, Yp[kk], 0, 0, 0);
      }
      f32x4 Y = (Yp[0] + Yp[1]) + (Yp[2] + Yp[3]);

      if (isO) {
        size_t ob = (size_t)(c * 32 + r0) * 2048 + h * 128 + v0 + l15;
#pragma unroll
        for (int r = 0; r < 4; ++r)
          obuf[ob + (size_t)r * 2048] = Y[r] + o.pB[r];
      } else {
        union { __hip_bfloat16 b[4]; unsigned long long u; } uh;
#pragma unroll
        for (int r = 0; r < 4; ++r)
          uh.b[r] = __float2bfloat16(o.pB[r] - Y[r]);
        *(unsigned long long*)(UTh + l15 * UTP + r0) = uh.u;
      }
      // decay multiply is register-only: overlap with barrier wait
#pragma unroll
      for (int mi = 0; mi < 2; ++mi) S[mi] *= o.pvv[mi];
      __syncthreads();

      {
        bf16x8 ubh = *(const bf16x8*)(UTh + l15 * UTP + l4 * 8);
#pragma unroll
        for (int mi = 0; mi < 2; ++mi)
          S[mi] = __builtin_amdgcn_mfma_f32_16x16x32_bf16(o.kah[mi], ubh, S[mi], 0, 0, 0);
      }

#pragma unroll
      for (int mi = 0; mi < 2; ++mi) {
        const int kd0 = (w * 2 + mi) * 16 + l4 * 4;
        union { __hip_bfloat16 b[4]; unsigned long long u; } sh, sl;
#pragma unroll
        for (int r = 0; r < 4; ++r) {
          __hip_bfloat16 hh = __float2bfloat16(S[mi][r]);
          sh.b[r] = hh;
          sl.b[r] = __float2bfloat16(S[mi][r] - __bfloat162float(hh));
        }
        *(unsigned long long*)(STh + l15 * STP + kd0) = sh.u;
        *(unsigned long long*)(STl + l15 * STP + kd0) = sl.u;
      }
      __syncthreads();
    };

    ChunkOps A_, B_;
    loadops(A_, 0);
    for (int c = 0; c < 64; c += 2) {
      loadops(B_, c + 1);
      body(A_, c);
      if (c + 2 < 64) loadops(A_, c + 2);
      body(B_, c + 1);
    }
  } else {
    // ---- gate GEMM path: gatebuf[2048][2048] = g1b(lda 256) @ Wg2T(ldb 128), K=128 ----
    __hip_bfloat16* As = (__hip_bfloat16*)smem;
    __hip_bfloat16* Bs = As + BM * BKK;
    const int b2 = blockIdx.x - 128;
    const int m0 = (b2 >> 4) * BM, n0 = (b2 & 15) * BN;
    const int wm = w >> 1, wn = w & 1;

    f32x4 acc[4][4] = {};

    for (int k0 = 0; k0 < 128; k0 += BKK) {
#pragma unroll
      for (int i = 0; i < 4; ++i) {
        const int c = (w * 4 + i) * 64 + lane;
        const int row = c >> 3;
        const int colb = (c & 7) * 8;
        __builtin_amdgcn_global_load_lds(
            (const __attribute__((address_space(1))) void*)(g1b + (size_t)(m0 + row) * 256 + k0 + colb),
            (__attribute__((address_space(3))) void*)(As + (size_t)c * 8), 16, 0, 0);
        __builtin_amdgcn_global_load_lds(
            (const __attribute__((address_space(1))) void*)(Wg2T + (size_t)(n0 + row) * 128 + k0 + colb),
            (__attribute__((address_space(3))) void*)(Bs + (size_t)c * 8), 16, 0, 0);
      }
      __syncthreads();
#pragma unroll
      for (int kk = 0; kk < BKK; kk += 32) {
        bf16x8 af[4], bfv[4];
#pragma unroll
        for (int mi = 0; mi < 4; ++mi)
          af[mi] = *(const bf16x8*)(As + (wm * 64 + mi * 16 + l15) * BKK + kk + l4 * 8);
#pragma unroll
        for (int ni = 0; ni < 4; ++ni)
          bfv[ni] = *(const bf16x8*)(Bs + (wn * 64 + ni * 16 + l15) * BKK + kk + l4 * 8);
#pragma unroll
        for (int mi = 0; mi < 4; ++mi)
#pragma unroll
          for (int ni = 0; ni < 4; ++ni)
            acc[mi][ni] = __builtin_amdgcn_mfma_f32_16x16x32_bf16(af[mi], bfv[ni], acc[mi][ni], 0, 0, 0);
      }
      __syncthreads();
    }

#pragma unroll
    for (int mi = 0; mi < 4; ++mi)
#pragma unroll
      for (int ni = 0; ni < 4; ++ni) {
        const int row = m0 + wm * 64 + mi * 16 + l4 * 4;
        const int col = n0 + wn * 64 + ni * 16 + l15;
#pragma unroll
        for (int r = 0; r < 4; ++r)
          gatebuf[(size_t)(row + r) * 2048 + col] = acc[mi][ni][r];
      }
  }
}

// ---------------- sigmoid-gated RMSNorm -> bf16 ----------------
__global__ __launch_bounds__(256) void rmsgate_kernel(
    const float* __restrict__ o, const float* __restrict__ gate,
    const float* __restrict__ bg2, const float* __restrict__ norm_w,
    __hip_bfloat16* __restrict__ og)
{
  int row = blockIdx.x * 4 + (threadIdx.x >> 6);   // s*16 + h
  int lane = threadIdx.x & 63;
  int s = row >> 4, h = row & 15;
  int j = lane * 2;
  const float* p = o + (size_t)row * 128 + j;
  f32x2 v = *(const f32x2*)p;
  float ss = v.x * v.x + v.y * v.y;
#pragma unroll
  for (int off = 32; off > 0; off >>= 1) ss += __shfl_xor(ss, off);
  float rs = rsqrtf(ss * (1.f / 128.f) + 1e-6f);
  int c = h * 128 + j;
  float g0 = gate[(size_t)s * 2048 + c] + bg2[c];
  float g1 = gate[(size_t)s * 2048 + c + 1] + bg2[c + 1];
  float o0 = v.x * rs * norm_w[j] * (1.f / (1.f + expf(-g0)));
  float o1 = v.y * rs * norm_w[j + 1] * (1.f / (1.f + expf(-g1)));
  union { __hip_bfloat16 b[2]; unsigned int u; } pk2;
  pk2.b[0] = __float2bfloat16(o0);
  pk2.b[1] = __float2bfloat16(o1);
  *(unsigned int*)((char*)og + ((size_t)s * 2048 + c) * 2) = pk2.u;
}

// =====================================================================
extern "C" void kernel_launch(void* const* d_in, const int* in_sizes, int n_in,
                              void* d_out, int out_size, void* d_ws, size_t ws_size,
                              hipStream_t stream)
{
  const float* x      = (const float*)d_in[0];
  const float* ve     = (const float*)d_in[1];
  const float* lam    = (const float*)d_in[2];
  const float* Wq     = (const float*)d_in[3];
  const float* Wk     = (const float*)d_in[4];
  const float* Wv     = (const float*)d_in[5];
  const float* cwq    = (const float*)d_in[6];
  const float* cwk    = (const float*)d_in[7];
  const float* cwv    = (const float*)d_in[8];
  const float* Wf1    = (const float*)d_in[9];
  const float* Wf2    = (const float*)d_in[10];
  const float* Wb     = (const float*)d_in[11];
  const float* A_log  = (const float*)d_in[12];
  const float* dtb    = (const float*)d_in[13];
  const float* Wg1    = (const float*)d_in[14];
  const float* Wg2    = (const float*)d_in[15];
  const float* bg2    = (const float*)d_in[16];
  const float* norm_w = (const float*)d_in[17];
  const float* Wo     = (const float*)d_in[18];
  float* out = (float*)d_out;

  const size_t S2 = (size_t)2048 * 2048;

  char* p = (char*)d_ws;
  auto alloc = [&](size_t bytes) { char* r = p; p += (bytes + 255) & ~(size_t)255; return r; };

  __hip_bfloat16* xb     = (__hip_bfloat16*)alloc(S2 * 2);
  __hip_bfloat16* WoT    = (__hip_bfloat16*)alloc(S2 * 2);
  __hip_bfloat16* Wf2hT  = (__hip_bfloat16*)alloc(2048 * 128 * 2);
  __hip_bfloat16* Wf2lT  = (__hip_bfloat16*)alloc(2048 * 128 * 2);
  __hip_bfloat16* Wg2T   = (__hip_bfloat16*)alloc(2048 * 128 * 2);
  __hip_bfloat16* Wfg1hT = (__hip_bfloat16*)alloc((size_t)256 * 2048 * 2);
  __hip_bfloat16* Wfg1lT = (__hip_bfloat16*)alloc((size_t)256 * 2048 * 2);
  __hip_bfloat16* f1g1h  = (__hip_bfloat16*)alloc((size_t)2048 * 256 * 2);
  __hip_bfloat16* f1g1l  = (__hip_bfloat16*)alloc((size_t)2048 * 256 * 2);
  float* betaT = (float*)alloc((size_t)2048 * 16 * 4);
  __hip_bfloat16* qkvb = (__hip_bfloat16*)alloc(3 * S2 * 2);  // [2048][6144] bf16 (24MB)
  float* gbuf  = (float*)alloc(S2 * 4);
  float* gatebuf = (float*)alloc(S2 * 4);
  float* uvS   = (float*)alloc(S2 * 4);
  float* olocS = (float*)alloc(S2 * 4);
  __hip_bfloat16* Xgh = (__hip_bfloat16*)alloc(S2 * 4);   // 16MB: 1024 hc x 64 rows x 128 cols bf16
  __hip_bfloat16* KTh = (__hip_bfloat16*)alloc(S2 * 2);   // 8MB: 1024 hc x 128 x 32 bf16
  float* Pg    = (float*)alloc((size_t)1024 * 128 * 4);

  // overlays (timeline-checked):
  __hip_bfloat16* WqkvT = (__hip_bfloat16*)uvS;
  __hip_bfloat16* xlo = (__hip_bfloat16*)((char*)olocS + S2 * 2);
  float* fpart = (float*)Xgh;
  float* obuf  = gbuf;                           // gbuf dead after kda_pref
  __hip_bfloat16* og = (__hip_bfloat16*)qkvb;    // qkvb dead after kda_pref; og = first 8MB

  // 1. merged prep: all weight transposes + x split-cast (one launch)
  prep_all_kernel<<<21504, 256, 0, stream>>>(x, xb, xlo, Wq, Wk, Wv, Wo, WqkvT, WoT,
                                             Wf1, Wg1, Wfg1hT, Wfg1lT,
                                             Wf2, Wg2, Wf2hT, Wf2lT, Wg2T);

  // 2. merged QKV projection via 6-phase 256x192 GEMM (grid 256 = full CU fill) -> bf16 qkv
  gemm_bt192<<<dim3(32, 8), 512, 0, stream>>>(xb, WqkvT, qkvb, 6144, 2048, 2048, 32);

  // 3. merged f1|g1 stage (split-K z=8, 3-pass split precision)
  gemm_btsplit<<<dim3(2, 16, 8), 256, 0, stream>>>(xb, xlo, Wfg1hT, Wfg1lT, fpart,
                                                   2048, 256, 2048, 2048, 256);
  reduce8_beta_kernel<<<640, 256, 0, stream>>>(fpart, f1g1h, f1g1l, (size_t)2048 * 256,
                                               x, Wb, betaT);

  // 4. f-path second stage: g = f1 @ Wf2 (split)
  gemm_btsplit<<<dim3(16, 16), 256, 0, stream>>>(f1g1h, f1g1l, Wf2hT, Wf2lT, gbuf,
                                                 2048, 2048, 256, 128, 128);

  // 5. fused prep + chunk-local precompute (reads bf16 qkv)
  kda_pref<<<1024, 256, 0, stream>>>(qkvb, ve, lam, cwq, cwk, cwv, gbuf, dtb, A_log, betaT,
                                     Xgh, KTh, uvS, olocS, Pg);

  // 6. dual-role: chunk scan (128 blocks, XCD-swizzled) + gate GEMM (256 blocks) in one launch
  kda_seq_gate<<<384, 256, 0, stream>>>(Xgh, KTh, uvS, olocS, Pg, obuf,
                                        f1g1h + 128, Wg2T, gatebuf);

  // 7. gated rmsnorm -> bf16 (og aliases qkvb[0:8MB])
  rmsgate_kernel<<<8192, 256, 0, stream>>>(obuf, gatebuf, bg2, norm_w, og);

  // 8. output projection
  gemm_bt<<<dim3(16, 16), 256, 0, stream>>>(og, WoT, out, 2048, 2048, 2048, 2048, 2048, 0);
}